// Round 11
// baseline (1087.060 us; speedup 1.0000x reference)
//
#include <hip/hip_runtime.h>
#include <math.h>

#define N_ 4096
#define V_ 4
#define C_ 256

typedef __attribute__((ext_vector_type(8))) short bf16x8;
typedef __attribute__((ext_vector_type(4))) float f32x4;

// ---------------- workspace byte offsets ----------------
#define OFF_R      0ull           // f32 R[v][n][c]      16MB
#define OFF_DNHI   16777216ull    // bf16                 8MB
#define OFF_DNLO   25165824ull    // bf16                 8MB
#define OFF_SFT    33554432ull    // fp8 sfT[v][c][n]     4MB
#define OFF_E      37748736ull    // fp8 E[m][n]         16MB
#define OFF_ET     54525952ull    // fp8 ET[n][m]        16MB
#define OFF_WTH    71303168ull    // bf16 WT hi 256x256 128KB
#define OFF_WTL    71434240ull    // bf16 WT lo        128KB
#define OFF_RPMAX  71565312ull    // 64x4096 f32 = 1048576B each
#define OFF_RPARG  72613888ull
#define OFF_RPSUM  73662464ull
#define OFF_CPMAX  74711040ull    // 64x4096 f32 = 1048576B each
#define OFF_CPARG  75759616ull
#define OFF_CPSUM  76808192ull
#define OFF_RARG   77856768ull    // 16KB each
#define OFF_RSUM   77873152ull
#define OFF_CARG   77889536ull
#define OFF_CSUM   77905920ull
#define OFF_RELWT  77922304ull
#define OFF_SQ     77938688ull
#define OFF_CNT    77938752ull

__device__ __forceinline__ unsigned short f2bf(float x) {
    unsigned int u = __float_as_uint(x);
    u += 0x7fffu + ((u >> 16) & 1u);
    return (unsigned short)(u >> 16);
}
__device__ __forceinline__ float bf2f(unsigned short h) {
    return __uint_as_float(((unsigned int)h) << 16);
}
__device__ __forceinline__ f32x4 mfma16(bf16x8 a, bf16x8 b, f32x4 c) {
    return __builtin_amdgcn_mfma_f32_16x16x32_bf16(a, b, c, 0, 0, 0);
}
__device__ __forceinline__ unsigned int pk4fp8(float x0, float x1, float x2, float x3) {
    int w = 0;
    w = __builtin_amdgcn_cvt_pk_fp8_f32(x0, x1, w, false);
    w = __builtin_amdgcn_cvt_pk_fp8_f32(x2, x3, w, true);
    return (unsigned int)w;
}

// ---- normalize + bf16 hi/lo split: dn[v][n][c] ----
__global__ void normalize_k(const float* __restrict__ desc,
                            unsigned short* __restrict__ dnh, unsigned short* __restrict__ dnl) {
    int row = blockIdx.x;            // n*V + v
    int n = row >> 2, v = row & 3;
    int c = threadIdx.x;
    float x = desc[(size_t)row * C_ + c];
    __shared__ float red[256];
    red[c] = x * x;
    __syncthreads();
    for (int s = 128; s > 0; s >>= 1) {
        if (c < s) red[c] += red[c + s];
        __syncthreads();
    }
    float inv = 1.0f / fmaxf(sqrtf(red[0]), 1e-12f);
    float y = x * inv;
    size_t o = ((size_t)v * N_ + n) * C_ + c;
    unsigned short h = f2bf(y);
    dnh[o] = h;
    dnl[o] = f2bf(y - bf2f(h));
}

// ---- WT[c][k] = W_rec[k][c], hi/lo bf16 split ----
__global__ void wrecT_k(const float* __restrict__ W, unsigned short* __restrict__ WTh,
                        unsigned short* __restrict__ WTl) {
    __shared__ float Tt[64 * 65];
    int k0 = blockIdx.x * 64, c0 = blockIdx.y * 64;
    int t = threadIdx.x;
    int kr = t >> 2, cq = (t & 3) * 16;
    const float* src = W + (size_t)(k0 + kr) * C_ + c0 + cq;
    for (int u = 0; u < 16; ++u) Tt[(cq + u) * 65 + kr] = src[u];
    __syncthreads();
    int cr = t >> 2, kq = (t & 3) * 16;
    unsigned short th[16] __attribute__((aligned(16)));
    unsigned short tl[16] __attribute__((aligned(16)));
    for (int u = 0; u < 16; ++u) {
        float x = Tt[cr * 65 + kq + u];
        unsigned short h = f2bf(x);
        th[u] = h; tl[u] = f2bf(x - bf2f(h));
    }
    size_t o = (size_t)(c0 + cr) * C_ + k0 + kq;
    *(uint4*)(WTh + o) = *(const uint4*)th;
    *(uint4*)(WTh + o + 8) = *(const uint4*)(th + 8);
    *(uint4*)(WTl + o) = *(const uint4*)tl;
    *(uint4*)(WTl + o + 8) = *(const uint4*)(tl + 8);
}

// ---- R = dn @ W_rec via split-bf16 MFMA; block 128x128, wave 64x64 ----
__global__ __launch_bounds__(256) void rmatmul_k(
    const unsigned short* __restrict__ Ah, const unsigned short* __restrict__ Al,
    const unsigned short* __restrict__ Bh, const unsigned short* __restrict__ Bl,
    float* __restrict__ R) {
    __shared__ unsigned short smem[4 * 128 * 40];
    unsigned short* sAh = smem;
    unsigned short* sAl = sAh + 128 * 40;
    unsigned short* sBh = sAl + 128 * 40;
    unsigned short* sBl = sBh + 128 * 40;
    int tid = threadIdx.x;
    int c0 = blockIdx.x * 128, m0 = blockIdx.y * 128;
    int w = tid >> 6, l = tid & 63, wm = w & 1, wn = w >> 1;
    int mr = l & 15, q = l >> 4;
    f32x4 acc[4][4];
#pragma unroll
    for (int a = 0; a < 4; ++a)
#pragma unroll
        for (int b = 0; b < 4; ++b)
#pragma unroll
            for (int u = 0; u < 4; ++u) acc[a][b][u] = 0.f;
    int r = tid >> 1, h = (tid & 1) * 16;
    for (int k0 = 0; k0 < C_; k0 += 32) {
        size_t ga = (size_t)(m0 + r) * C_ + k0 + h;
        size_t gb = (size_t)(c0 + r) * C_ + k0 + h;
        uint4 a0 = *(const uint4*)(Ah + ga);
        uint4 a1 = *(const uint4*)(Ah + ga + 8);
        uint4 a2 = *(const uint4*)(Al + ga);
        uint4 a3 = *(const uint4*)(Al + ga + 8);
        uint4 b0 = *(const uint4*)(Bh + gb);
        uint4 b1 = *(const uint4*)(Bh + gb + 8);
        uint4 b2 = *(const uint4*)(Bl + gb);
        uint4 b3 = *(const uint4*)(Bl + gb + 8);
        *(uint4*)(sAh + r * 40 + h)     = a0;
        *(uint4*)(sAh + r * 40 + h + 8) = a1;
        *(uint4*)(sAl + r * 40 + h)     = a2;
        *(uint4*)(sAl + r * 40 + h + 8) = a3;
        *(uint4*)(sBh + r * 40 + h)     = b0;
        *(uint4*)(sBh + r * 40 + h + 8) = b1;
        *(uint4*)(sBl + r * 40 + h)     = b2;
        *(uint4*)(sBl + r * 40 + h + 8) = b3;
        __syncthreads();
        bf16x8 fah[4], fal[4], fbh[4], fbl[4];
#pragma unroll
        for (int ti = 0; ti < 4; ++ti) {
            int row = wm * 64 + ti * 16 + mr;
            fah[ti] = *(const bf16x8*)(sAh + row * 40 + q * 8);
            fal[ti] = *(const bf16x8*)(sAl + row * 40 + q * 8);
        }
#pragma unroll
        for (int tj = 0; tj < 4; ++tj) {
            int row = wn * 64 + tj * 16 + mr;
            fbh[tj] = *(const bf16x8*)(sBh + row * 40 + q * 8);
            fbl[tj] = *(const bf16x8*)(sBl + row * 40 + q * 8);
        }
#pragma unroll
        for (int ti = 0; ti < 4; ++ti)
#pragma unroll
            for (int tj = 0; tj < 4; ++tj) acc[ti][tj] = mfma16(fah[ti], fbh[tj], acc[ti][tj]);
#pragma unroll
        for (int ti = 0; ti < 4; ++ti)
#pragma unroll
            for (int tj = 0; tj < 4; ++tj) acc[ti][tj] = mfma16(fah[ti], fbl[tj], acc[ti][tj]);
#pragma unroll
        for (int ti = 0; ti < 4; ++ti)
#pragma unroll
            for (int tj = 0; tj < 4; ++tj) acc[ti][tj] = mfma16(fal[ti], fbh[tj], acc[ti][tj]);
        __syncthreads();
    }
#pragma unroll
    for (int ti = 0; ti < 4; ++ti)
#pragma unroll
        for (int tj = 0; tj < 4; ++tj) {
            int c = c0 + wn * 64 + tj * 16 + mr;
#pragma unroll
            for (int rg = 0; rg < 4; ++rg) {
                int m = m0 + wm * 64 + ti * 16 + q * 4 + rg;
                R[(size_t)m * C_ + c] = acc[ti][tj][rg];
            }
        }
}

// ---- relWT[p][c], p = i*4+j ----
__global__ void relwt_k(const float* __restrict__ T, const float* __restrict__ WT,
                        float* __restrict__ relwt) {
    int p = blockIdx.x; int i = p >> 2, j = p & 3;
    if (i == j) return;
    int c = threadIdx.x;
    float acc = 0.f;
    for (int k = 0; k < 16; ++k) acc += T[i * 16 + k] * WT[(size_t)k * C_ + c];
    for (int k = 0; k < 16; ++k) acc += T[j * 16 + k] * WT[(size_t)(16 + k) * C_ + c];
    relwt[(size_t)p * C_ + c] = acc;
}

// ---- sf8T[v][c][n] = fp8(sf[n][v][c]) ----
__global__ void sfT_k(const float* __restrict__ sf, unsigned char* __restrict__ sf8T) {
    __shared__ float Tt[64 * 65];
    int n0 = blockIdx.x * 64, c0 = blockIdx.y * 64, v = blockIdx.z;
    int t = threadIdx.x;
    int nr = t >> 2, cq = (t & 3) * 16;
    const float* src = sf + ((size_t)(n0 + nr) * V_ + v) * C_ + c0 + cq;
    for (int u = 0; u < 16; ++u) Tt[(cq + u) * 65 + nr] = src[u];
    __syncthreads();
    int cr = t >> 2, nq = (t & 3) * 16;
    unsigned int wb[4];
#pragma unroll
    for (int g = 0; g < 4; ++g) {
        const float* p = Tt + cr * 65 + nq + g * 4;
        wb[g] = pk4fp8(p[0], p[1], p[2], p[3]);
    }
    unsigned char* dst = sf8T + ((size_t)v * C_ + c0 + cr) * N_ + n0 + nq;
    *(uint4*)dst = make_uint4(wb[0], wb[1], wb[2], wb[3]);
}

__global__ void zero_k(float* sq, int* cnt) {
    if (threadIdx.x < 16) { sq[threadIdx.x] = 0.f; cnt[threadIdx.x] = 0; }
}

// ---- sim v4: 64x64 tile, K-loop reads MFMA fragments DIRECTLY from global ----
// NT layout == fragment layout: lane(q*16+mr) holds A[m0+mr][k0+q*8..+8].
// No LDS staging, no K-loop barriers; LDS only for the epilogue tile.
__global__ __launch_bounds__(256) void sim_mfma_k(
    const unsigned short* __restrict__ Ahi, const unsigned short* __restrict__ Alo,
    const unsigned short* __restrict__ Bhi, const unsigned short* __restrict__ Blo,
    unsigned char* __restrict__ E8, unsigned char* __restrict__ ET8,
    float* __restrict__ rpMax, int* __restrict__ rpArg, float* __restrict__ rpSum,
    float* __restrict__ cpMax, int* __restrict__ cpArg, float* __restrict__ cpSum) {
    __shared__ float S[64 * 65];         // exp(S) tile
    __shared__ float sRedM[256];
    __shared__ int   sRedA[256];
    __shared__ float sRedS[256];

    int tid = threadIdx.x;
    int m0 = blockIdx.y * 64, n0 = blockIdx.x * 64;
    int w = tid >> 6, l = tid & 63;
    int wm = w & 1, wn = w >> 1;
    int mr = l & 15, q = l >> 4;

    f32x4 acc[2][2];
#pragma unroll
    for (int a = 0; a < 2; ++a)
#pragma unroll
        for (int b = 0; b < 2; ++b)
#pragma unroll
            for (int u = 0; u < 4; ++u) acc[a][b][u] = 0.f;

    // per-lane fragment base pointers (row-major over k)
    size_t aoff = (size_t)(m0 + wm * 32 + mr) * C_ + q * 8;
    size_t boff = (size_t)(n0 + wn * 32 + mr) * C_ + q * 8;
    const unsigned short* pAh0 = Ahi + aoff;
    const unsigned short* pAh1 = pAh0 + 16 * C_;
    const unsigned short* pAl0 = Alo + aoff;
    const unsigned short* pAl1 = pAl0 + 16 * C_;
    const unsigned short* pBh0 = Bhi + boff;
    const unsigned short* pBh1 = pBh0 + 16 * C_;
    const unsigned short* pBl0 = Blo + boff;
    const unsigned short* pBl1 = pBl0 + 16 * C_;

#pragma unroll
    for (int k0 = 0; k0 < C_; k0 += 32) {
        bf16x8 ah0 = *(const bf16x8*)(pAh0 + k0);
        bf16x8 ah1 = *(const bf16x8*)(pAh1 + k0);
        bf16x8 al0 = *(const bf16x8*)(pAl0 + k0);
        bf16x8 al1 = *(const bf16x8*)(pAl1 + k0);
        bf16x8 bh0 = *(const bf16x8*)(pBh0 + k0);
        bf16x8 bh1 = *(const bf16x8*)(pBh1 + k0);
        bf16x8 bl0 = *(const bf16x8*)(pBl0 + k0);
        bf16x8 bl1 = *(const bf16x8*)(pBl1 + k0);
        acc[0][0] = mfma16(ah0, bh0, acc[0][0]);
        acc[0][1] = mfma16(ah0, bh1, acc[0][1]);
        acc[1][0] = mfma16(ah1, bh0, acc[1][0]);
        acc[1][1] = mfma16(ah1, bh1, acc[1][1]);
        acc[0][0] = mfma16(ah0, bl0, acc[0][0]);
        acc[0][1] = mfma16(ah0, bl1, acc[0][1]);
        acc[1][0] = mfma16(ah1, bl0, acc[1][0]);
        acc[1][1] = mfma16(ah1, bl1, acc[1][1]);
        acc[0][0] = mfma16(al0, bh0, acc[0][0]);
        acc[0][1] = mfma16(al0, bh1, acc[0][1]);
        acc[1][0] = mfma16(al1, bh0, acc[1][0]);
        acc[1][1] = mfma16(al1, bh1, acc[1][1]);
    }

    // ---- epilogue: exp once into LDS (monotone -> argmax/sum equivalent) ----
#pragma unroll
    for (int ti = 0; ti < 2; ++ti)
#pragma unroll
        for (int tj = 0; tj < 2; ++tj)
#pragma unroll
            for (int rg = 0; rg < 4; ++rg)
                S[(wm * 32 + ti * 16 + q * 4 + rg) * 65 + wn * 32 + tj * 16 + mr] =
                    __expf(acc[ti][tj][rg]);
    __syncthreads();

    // row stats
    {
        int rr = tid >> 2, q4 = tid & 3;
        float mx = -1e30f; int ag = 0; float sm = 0.f;
        for (int cc = 0; cc < 16; ++cc) {
            int c = q4 * 16 + cc;
            float v = S[rr * 65 + c];
            sm += v;
            if (v > mx) { mx = v; ag = c; }
        }
        sRedM[tid] = mx; sRedA[tid] = ag; sRedS[tid] = sm;
    }
    __syncthreads();
    if (tid < 64) {
        float mx = -1e30f; int ag = 0; float sm = 0.f;
        for (int qq = 0; qq < 4; ++qq) {
            float v = sRedM[tid * 4 + qq];
            if (v > mx) { mx = v; ag = sRedA[tid * 4 + qq]; }
            sm += sRedS[tid * 4 + qq];
        }
        size_t o = (size_t)blockIdx.x * N_ + m0 + tid;
        rpMax[o] = mx; rpArg[o] = n0 + ag; rpSum[o] = sm;
    }
    __syncthreads();
    // col stats
    {
        int cc = tid >> 2, q4 = tid & 3;
        float mx = -1e30f; int ag = 0; float sm = 0.f;
        for (int rr = 0; rr < 16; ++rr) {
            int rrr = q4 * 16 + rr;
            float v = S[rrr * 65 + cc];
            sm += v;
            if (v > mx) { mx = v; ag = rrr; }
        }
        sRedM[tid] = mx; sRedA[tid] = ag; sRedS[tid] = sm;
    }
    __syncthreads();
    if (tid < 64) {
        float mx = -1e30f; int ag = 0; float sm = 0.f;
        for (int qq = 0; qq < 4; ++qq) {
            float v = sRedM[tid * 4 + qq];
            if (v > mx) { mx = v; ag = sRedA[tid * 4 + qq]; }
            sm += sRedS[tid * 4 + qq];
        }
        size_t o = (size_t)blockIdx.y * N_ + n0 + tid;
        cpMax[o] = mx; cpArg[o] = m0 + ag; cpSum[o] = sm;
    }
    // E store (fp8), row-major
    {
        int r2 = tid >> 2, cq = (tid & 3) * 16;
        unsigned int wb[4];
#pragma unroll
        for (int g = 0; g < 4; ++g) {
            const float* p = S + r2 * 65 + cq + g * 4;
            wb[g] = pk4fp8(p[0], p[1], p[2], p[3]);
        }
        *(uint4*)(E8 + (size_t)(m0 + r2) * N_ + n0 + cq) = make_uint4(wb[0], wb[1], wb[2], wb[3]);
    }
    // ET store (fp8), row-major in n
    {
        int n2 = tid >> 2, mq = (tid & 3) * 16;
        unsigned int wb[4];
#pragma unroll
        for (int g = 0; g < 4; ++g) {
            wb[g] = pk4fp8(S[(mq + g * 4 + 0) * 65 + n2], S[(mq + g * 4 + 1) * 65 + n2],
                           S[(mq + g * 4 + 2) * 65 + n2], S[(mq + g * 4 + 3) * 65 + n2]);
        }
        *(uint4*)(ET8 + (size_t)(n0 + n2) * N_ + m0 + mq) = make_uint4(wb[0], wb[1], wb[2], wb[3]);
    }
}

// ---- fused merge of row/col tile-partials; grid (64, 2), 64 tiles each ----
__global__ __launch_bounds__(256) void merge_k(
    const float* __restrict__ rpMax, const int* __restrict__ rpArg,
    const float* __restrict__ rpSum, const float* __restrict__ cpMax,
    const int* __restrict__ cpArg, const float* __restrict__ cpSum,
    int* __restrict__ rowArg, float* __restrict__ rowSum,
    int* __restrict__ colArg, float* __restrict__ colSum) {
    int d = blockIdx.y;
    const float* pMax = d ? cpMax : rpMax;
    const int*   pArg = d ? cpArg : rpArg;
    const float* pSum = d ? cpSum : rpSum;
    int*   outArg = d ? colArg : rowArg;
    float* outSum = d ? colSum : rowSum;
    int tid = threadIdx.x;
    int li = tid & 63, g = tid >> 6;
    int m = blockIdx.x * 64 + li;
    float mx = -1e30f; int ag = 0; float sm = 0.f;
    for (int t = g * 16; t < g * 16 + 16; ++t) {
        float v = pMax[(size_t)t * N_ + m];
        if (v > mx) { mx = v; ag = pArg[(size_t)t * N_ + m]; }
        sm += pSum[(size_t)t * N_ + m];
    }
    __shared__ float sMx[256], sSm[256];
    __shared__ int sAg[256];
    sMx[g * 64 + li] = mx; sAg[g * 64 + li] = ag; sSm[g * 64 + li] = sm;
    __syncthreads();
    if (tid < 64) {
        float M = sMx[tid]; int A = sAg[tid]; float Ssum = sSm[tid];
        for (int gg = 1; gg < 4; ++gg) {
            float v = sMx[gg * 64 + tid];
            if (v > M) { M = v; A = sAg[gg * 64 + tid]; }
            Ssum += sSm[gg * 64 + tid];
        }
        outArg[m] = A; outSum[m] = Ssum;
    }
}

// ---- pass2: fp8 GEMM (32m x 64c, K=4096) + fused loss; XCD-swizzled ----
__global__ __launch_bounds__(256) void p2_k(
    const unsigned char* __restrict__ E8, const unsigned char* __restrict__ ET8,
    const unsigned char* __restrict__ sf8T, int iview, int jview,
    const int* __restrict__ rowArg, const int* __restrict__ colArg,
    const float* __restrict__ rowSum, const float* __restrict__ colSum,
    const float* __restrict__ Ri, const float* __restrict__ Rj,
    const float* __restrict__ relwt, int pid0, int pid1,
    float* __restrict__ pairSq, int* __restrict__ pairCnt) {
    __shared__ unsigned char sA[32 * 144];
    __shared__ unsigned char sB[64 * 144];
    __shared__ float red[256];
    __shared__ int   mutS[32];
    __shared__ float invS[32];
    int tid = threadIdx.x;
    int lin = blockIdx.x;
    int xcd = lin & 7, slot = lin >> 3;
    int grp = xcd + 8 * (slot >> 2);
    int ct = slot & 3;
    int mt = grp & 127, d = grp >> 7;
    const unsigned char* A = d ? ET8 : E8;
    const unsigned char* B = sf8T + (size_t)(d ? iview : jview) * C_ * N_;
    const int* fa = d ? colArg : rowArg;
    const int* ba = d ? rowArg : colArg;
    const float* sumE = d ? colSum : rowSum;
    const float* Rr = d ? Rj : Ri;
    int pid = d ? pid1 : pid0;
    int c0 = ct * 64, m0 = mt * 32;
    int w = tid >> 6, l = tid & 63, wm = w & 1, wn = w >> 1;
    int mr = l & 15, q = l >> 4;
    if (tid < 32) {
        int y = m0 + tid;
        mutS[tid] = (ba[fa[y]] == y) ? 1 : 0;
        invS[tid] = 1.0f / sumE[y];
    }
    f32x4 acc[2];
#pragma unroll
    for (int b = 0; b < 2; ++b)
#pragma unroll
        for (int u = 0; u < 4; ++u) acc[b][u] = 0.f;

    int ra = tid >> 3, ka = (tid & 7) * 16;
    int rb = tid >> 2, kb = (tid & 3) * 32;
    const unsigned char* Arow = A + (size_t)(m0 + ra) * N_;
    const unsigned char* Brow = B + (size_t)(c0 + rb) * N_;
    uint4 pa  = *(const uint4*)(Arow + ka);
    uint4 pb0 = *(const uint4*)(Brow + kb);
    uint4 pb1 = *(const uint4*)(Brow + kb + 16);
    for (int k0 = 0; k0 < N_; k0 += 128) {
        *(uint4*)(sA + ra * 144 + ka)      = pa;
        *(uint4*)(sB + rb * 144 + kb)      = pb0;
        *(uint4*)(sB + rb * 144 + kb + 16) = pb1;
        __syncthreads();
        int kn = k0 + 128;
        if (kn < N_) {
            pa  = *(const uint4*)(Arow + kn + ka);
            pb0 = *(const uint4*)(Brow + kn + kb);
            pb1 = *(const uint4*)(Brow + kn + kb + 16);
        }
#pragma unroll
        for (int ksub = 0; ksub < 128; ksub += 32) {
            long af = *(const long*)(sA + (wm * 16 + mr) * 144 + ksub + q * 8);
            long b0 = *(const long*)(sB + (wn * 32 + mr) * 144 + ksub + q * 8);
            long b1 = *(const long*)(sB + (wn * 32 + 16 + mr) * 144 + ksub + q * 8);
            acc[0] = __builtin_amdgcn_mfma_f32_16x16x32_fp8_fp8(af, b0, acc[0], 0, 0, 0);
            acc[1] = __builtin_amdgcn_mfma_f32_16x16x32_fp8_fp8(af, b1, acc[1], 0, 0, 0);
        }
        __syncthreads();
    }
    const float* rw = relwt + (size_t)pid * C_;
    float local = 0.f;
#pragma unroll
    for (int tj = 0; tj < 2; ++tj) {
        int c = c0 + wn * 32 + tj * 16 + mr;
        float rwc = rw[c];
#pragma unroll
        for (int rg = 0; rg < 4; ++rg) {
            int ml = wm * 16 + q * 4 + rg;
            if (mutS[ml]) {
                int m = m0 + ml;
                float soft = acc[tj][rg] * invS[ml];
                float dv = Rr[(size_t)m * C_ + c] + rwc - soft;
                local += dv * dv;
            }
        }
    }
    red[tid] = local;
    __syncthreads();
    for (int s = 128; s > 0; s >>= 1) {
        if (tid < s) red[tid] += red[tid + s];
        __syncthreads();
    }
    if (tid == 0) {
        atomicAdd(pairSq + pid, red[0]);
        if (ct == 0) {
            int cnt = 0;
            for (int u = 0; u < 32; ++u) cnt += mutS[u];
            atomicAdd(pairCnt + pid, cnt);
        }
    }
}

// ---- final scalar combine ----
__global__ void final_k(const float* __restrict__ sq, const int* __restrict__ cnt,
                        float* __restrict__ out) {
    if (threadIdx.x == 0 && blockIdx.x == 0) {
        float loss = 0.f, count = 0.f;
        for (int p = 0; p < 16; ++p) {
            int i = p >> 2, j = p & 3;
            if (i == j) continue;
            float ns = (float)cnt[p];
            if (ns > 0.f) { loss += sq[p] / fmaxf(ns * (float)C_, 1.0f); count += 1.f; }
        }
        out[0] = (count > 0.f) ? loss / count : 0.f;
    }
}

extern "C" void kernel_launch(void* const* d_in, const int* in_sizes, int n_in,
                              void* d_out, int out_size, void* d_ws, size_t ws_size,
                              hipStream_t stream) {
    const float* desc = (const float*)d_in[0];
    const float* sf   = (const float*)d_in[1];
    const float* T    = (const float*)d_in[2];
    const float* Wrec = (const float*)d_in[3];
    const float* WT   = (const float*)d_in[4];
    float* out = (float*)d_out;
    char* ws = (char*)d_ws;

    float*          R     = (float*)(ws + OFF_R);
    unsigned short* dnh   = (unsigned short*)(ws + OFF_DNHI);
    unsigned short* dnl   = (unsigned short*)(ws + OFF_DNLO);
    unsigned char*  sf8T  = (unsigned char*)(ws + OFF_SFT);
    unsigned char*  E8    = (unsigned char*)(ws + OFF_E);
    unsigned char*  ET8   = (unsigned char*)(ws + OFF_ET);
    unsigned short* WTh   = (unsigned short*)(ws + OFF_WTH);
    unsigned short* WTl   = (unsigned short*)(ws + OFF_WTL);
    float* rpMax = (float*)(ws + OFF_RPMAX);
    int*   rpArg = (int*)(ws + OFF_RPARG);
    float* rpSum = (float*)(ws + OFF_RPSUM);
    float* cpMax = (float*)(ws + OFF_CPMAX);
    int*   cpArg = (int*)(ws + OFF_CPARG);
    float* cpSum = (float*)(ws + OFF_CPSUM);
    int*   rowArg = (int*)(ws + OFF_RARG);
    float* rowSum = (float*)(ws + OFF_RSUM);
    int*   colArg = (int*)(ws + OFF_CARG);
    float* colSum = (float*)(ws + OFF_CSUM);
    float* relwt = (float*)(ws + OFF_RELWT);
    float* pairSq = (float*)(ws + OFF_SQ);
    int*   pairCnt = (int*)(ws + OFF_CNT);

    normalize_k<<<N_ * V_, 256, 0, stream>>>(desc, dnh, dnl);
    wrecT_k<<<dim3(4, 4), 256, 0, stream>>>(Wrec, WTh, WTl);
    rmatmul_k<<<dim3(2, 128), 256, 0, stream>>>(dnh, dnl, WTh, WTl, R);
    sfT_k<<<dim3(64, 4, 4), 256, 0, stream>>>(sf, sf8T);
    relwt_k<<<16, 256, 0, stream>>>(T, WT, relwt);
    zero_k<<<1, 64, 0, stream>>>(pairSq, pairCnt);

    for (int i = 0; i < V_; ++i) {
        for (int j = i + 1; j < V_; ++j) {
            const unsigned short* Ahi = dnh + (size_t)i * N_ * C_;
            const unsigned short* Alo = dnl + (size_t)i * N_ * C_;
            const unsigned short* Bhi = dnh + (size_t)j * N_ * C_;
            const unsigned short* Blo = dnl + (size_t)j * N_ * C_;
            sim_mfma_k<<<dim3(64, 64), 256, 0, stream>>>(
                Ahi, Alo, Bhi, Blo, E8, ET8, rpMax, rpArg, rpSum, cpMax, cpArg, cpSum);
            merge_k<<<dim3(64, 2), 256, 0, stream>>>(
                rpMax, rpArg, rpSum, cpMax, cpArg, cpSum, rowArg, rowSum, colArg, colSum);
            int pid0 = i * 4 + j, pid1 = j * 4 + i;
            p2_k<<<1024, 256, 0, stream>>>(
                E8, ET8, sf8T, i, j, rowArg, colArg, rowSum, colSum,
                R + (size_t)i * N_ * C_, R + (size_t)j * N_ * C_,
                relwt, pid0, pid1, pairSq, pairCnt);
        }
    }
    final_k<<<1, 64, 0, stream>>>(pairSq, pairCnt, out);
}

// Round 12
// 562.731 us; speedup vs baseline: 1.9318x; 1.9318x over previous
//
#include <hip/hip_runtime.h>
#include <math.h>

#define N_ 4096
#define V_ 4
#define C_ 256

typedef __attribute__((ext_vector_type(8))) short bf16x8;
typedef __attribute__((ext_vector_type(4))) float f32x4;
typedef unsigned long long u64;

// ---------------- workspace byte offsets ----------------
#define OFF_R      0ull            // f32 R[v][n][c]          16MB
#define OFF_DNHI   16777216ull     // bf16                     8MB
#define OFF_DNLO   25165824ull     // bf16                     8MB
#define OFF_SFT    33554432ull     // fp8 sfT[v][c][n]         4MB
#define OFF_E      37748736ull     // fp8 E slots x3          48MB
#define OFF_ET     88080384ull     // fp8 ET slots x3         48MB
#define OFF_WTH    138412032ull    // bf16 WT hi 256x256     128KB
#define OFF_WTL    138543104ull
#define OFF_ROWPK  138674176ull    // u64 rowPk[6][4096]     192KB
#define OFF_COLPK  138870784ull    // u64 colPk[6][4096]
#define OFF_ROWSM  139067392ull    // f32 rowSm[6][4096]      96KB
#define OFF_COLSM  139165696ull
#define OFF_RELWT  139264000ull    // f32 16x256
#define OFF_SQ     139280384ull
#define OFF_CNT    139280448ull

__device__ __forceinline__ unsigned short f2bf(float x) {
    unsigned int u = __float_as_uint(x);
    u += 0x7fffu + ((u >> 16) & 1u);
    return (unsigned short)(u >> 16);
}
__device__ __forceinline__ float bf2f(unsigned short h) {
    return __uint_as_float(((unsigned int)h) << 16);
}
__device__ __forceinline__ f32x4 mfma16(bf16x8 a, bf16x8 b, f32x4 c) {
    return __builtin_amdgcn_mfma_f32_16x16x32_bf16(a, b, c, 0, 0, 0);
}
__device__ __forceinline__ unsigned int pk4fp8(float x0, float x1, float x2, float x3) {
    int w = 0;
    w = __builtin_amdgcn_cvt_pk_fp8_f32(x0, x1, w, false);
    w = __builtin_amdgcn_cvt_pk_fp8_f32(x2, x3, w, true);
    return (unsigned int)w;
}

// ---- normalize + bf16 hi/lo split: dn[v][n][c] ----
__global__ void normalize_k(const float* __restrict__ desc,
                            unsigned short* __restrict__ dnh, unsigned short* __restrict__ dnl) {
    int row = blockIdx.x;            // n*V + v
    int n = row >> 2, v = row & 3;
    int c = threadIdx.x;
    float x = desc[(size_t)row * C_ + c];
    __shared__ float red[256];
    red[c] = x * x;
    __syncthreads();
    for (int s = 128; s > 0; s >>= 1) {
        if (c < s) red[c] += red[c + s];
        __syncthreads();
    }
    float inv = 1.0f / fmaxf(sqrtf(red[0]), 1e-12f);
    float y = x * inv;
    size_t o = ((size_t)v * N_ + n) * C_ + c;
    unsigned short h = f2bf(y);
    dnh[o] = h;
    dnl[o] = f2bf(y - bf2f(h));
}

// ---- WT[c][k] = W_rec[k][c], hi/lo bf16 split ----
__global__ void wrecT_k(const float* __restrict__ W, unsigned short* __restrict__ WTh,
                        unsigned short* __restrict__ WTl) {
    __shared__ float Tt[64 * 65];
    int k0 = blockIdx.x * 64, c0 = blockIdx.y * 64;
    int t = threadIdx.x;
    int kr = t >> 2, cq = (t & 3) * 16;
    const float* src = W + (size_t)(k0 + kr) * C_ + c0 + cq;
    for (int u = 0; u < 16; ++u) Tt[(cq + u) * 65 + kr] = src[u];
    __syncthreads();
    int cr = t >> 2, kq = (t & 3) * 16;
    unsigned short th[16] __attribute__((aligned(16)));
    unsigned short tl[16] __attribute__((aligned(16)));
    for (int u = 0; u < 16; ++u) {
        float x = Tt[cr * 65 + kq + u];
        unsigned short h = f2bf(x);
        th[u] = h; tl[u] = f2bf(x - bf2f(h));
    }
    size_t o = (size_t)(c0 + cr) * C_ + k0 + kq;
    *(uint4*)(WTh + o) = *(const uint4*)th;
    *(uint4*)(WTh + o + 8) = *(const uint4*)(th + 8);
    *(uint4*)(WTl + o) = *(const uint4*)tl;
    *(uint4*)(WTl + o + 8) = *(const uint4*)(tl + 8);
}

// ---- R = dn @ W_rec via split-bf16 MFMA; block 128x128, wave 64x64 ----
__global__ __launch_bounds__(256) void rmatmul_k(
    const unsigned short* __restrict__ Ah, const unsigned short* __restrict__ Al,
    const unsigned short* __restrict__ Bh, const unsigned short* __restrict__ Bl,
    float* __restrict__ R) {
    __shared__ unsigned short smem[4 * 128 * 40];
    unsigned short* sAh = smem;
    unsigned short* sAl = sAh + 128 * 40;
    unsigned short* sBh = sAl + 128 * 40;
    unsigned short* sBl = sBh + 128 * 40;
    int tid = threadIdx.x;
    int c0 = blockIdx.x * 128, m0 = blockIdx.y * 128;
    int w = tid >> 6, l = tid & 63, wm = w & 1, wn = w >> 1;
    int mr = l & 15, q = l >> 4;
    f32x4 acc[4][4];
#pragma unroll
    for (int a = 0; a < 4; ++a)
#pragma unroll
        for (int b = 0; b < 4; ++b)
#pragma unroll
            for (int u = 0; u < 4; ++u) acc[a][b][u] = 0.f;
    int r = tid >> 1, h = (tid & 1) * 16;
    for (int k0 = 0; k0 < C_; k0 += 32) {
        size_t ga = (size_t)(m0 + r) * C_ + k0 + h;
        size_t gb = (size_t)(c0 + r) * C_ + k0 + h;
        uint4 a0 = *(const uint4*)(Ah + ga);
        uint4 a1 = *(const uint4*)(Ah + ga + 8);
        uint4 a2 = *(const uint4*)(Al + ga);
        uint4 a3 = *(const uint4*)(Al + ga + 8);
        uint4 b0 = *(const uint4*)(Bh + gb);
        uint4 b1 = *(const uint4*)(Bh + gb + 8);
        uint4 b2 = *(const uint4*)(Bl + gb);
        uint4 b3 = *(const uint4*)(Bl + gb + 8);
        *(uint4*)(sAh + r * 40 + h)     = a0;
        *(uint4*)(sAh + r * 40 + h + 8) = a1;
        *(uint4*)(sAl + r * 40 + h)     = a2;
        *(uint4*)(sAl + r * 40 + h + 8) = a3;
        *(uint4*)(sBh + r * 40 + h)     = b0;
        *(uint4*)(sBh + r * 40 + h + 8) = b1;
        *(uint4*)(sBl + r * 40 + h)     = b2;
        *(uint4*)(sBl + r * 40 + h + 8) = b3;
        __syncthreads();
        bf16x8 fah[4], fal[4], fbh[4], fbl[4];
#pragma unroll
        for (int ti = 0; ti < 4; ++ti) {
            int row = wm * 64 + ti * 16 + mr;
            fah[ti] = *(const bf16x8*)(sAh + row * 40 + q * 8);
            fal[ti] = *(const bf16x8*)(sAl + row * 40 + q * 8);
        }
#pragma unroll
        for (int tj = 0; tj < 4; ++tj) {
            int row = wn * 64 + tj * 16 + mr;
            fbh[tj] = *(const bf16x8*)(sBh + row * 40 + q * 8);
            fbl[tj] = *(const bf16x8*)(sBl + row * 40 + q * 8);
        }
#pragma unroll
        for (int ti = 0; ti < 4; ++ti)
#pragma unroll
            for (int tj = 0; tj < 4; ++tj) acc[ti][tj] = mfma16(fah[ti], fbh[tj], acc[ti][tj]);
#pragma unroll
        for (int ti = 0; ti < 4; ++ti)
#pragma unroll
            for (int tj = 0; tj < 4; ++tj) acc[ti][tj] = mfma16(fah[ti], fbl[tj], acc[ti][tj]);
#pragma unroll
        for (int ti = 0; ti < 4; ++ti)
#pragma unroll
            for (int tj = 0; tj < 4; ++tj) acc[ti][tj] = mfma16(fal[ti], fbh[tj], acc[ti][tj]);
        __syncthreads();
    }
#pragma unroll
    for (int ti = 0; ti < 4; ++ti)
#pragma unroll
        for (int tj = 0; tj < 4; ++tj) {
            int c = c0 + wn * 64 + tj * 16 + mr;
#pragma unroll
            for (int rg = 0; rg < 4; ++rg) {
                int m = m0 + wm * 64 + ti * 16 + q * 4 + rg;
                R[(size_t)m * C_ + c] = acc[ti][tj][rg];
            }
        }
}

// ---- relWT[p][c], p = i*4+j ----
__global__ void relwt_k(const float* __restrict__ T, const float* __restrict__ WT,
                        float* __restrict__ relwt) {
    int p = blockIdx.x; int i = p >> 2, j = p & 3;
    if (i == j) return;
    int c = threadIdx.x;
    float acc = 0.f;
    for (int k = 0; k < 16; ++k) acc += T[i * 16 + k] * WT[(size_t)k * C_ + c];
    for (int k = 0; k < 16; ++k) acc += T[j * 16 + k] * WT[(size_t)(16 + k) * C_ + c];
    relwt[(size_t)p * C_ + c] = acc;
}

// ---- sf8T[v][c][n] = fp8(sf[n][v][c]) ----
__global__ void sfT_k(const float* __restrict__ sf, unsigned char* __restrict__ sf8T) {
    __shared__ float Tt[64 * 65];
    int n0 = blockIdx.x * 64, c0 = blockIdx.y * 64, v = blockIdx.z;
    int t = threadIdx.x;
    int nr = t >> 2, cq = (t & 3) * 16;
    const float* src = sf + ((size_t)(n0 + nr) * V_ + v) * C_ + c0 + cq;
    for (int u = 0; u < 16; ++u) Tt[(cq + u) * 65 + nr] = src[u];
    __syncthreads();
    int cr = t >> 2, nq = (t & 3) * 16;
    unsigned int wb[4];
#pragma unroll
    for (int g = 0; g < 4; ++g) {
        const float* p = Tt + cr * 65 + nq + g * 4;
        wb[g] = pk4fp8(p[0], p[1], p[2], p[3]);
    }
    unsigned char* dst = sf8T + ((size_t)v * C_ + c0 + cr) * N_ + n0 + nq;
    *(uint4*)dst = make_uint4(wb[0], wb[1], wb[2], wb[3]);
}

// ---- zero stats (all 6 slots) + pair accumulators ----
__global__ void zero_k(u64* rowPk, u64* colPk, float* rowSm, float* colSm,
                       float* sq, int* cnt) {
    int idx = blockIdx.x * 256 + threadIdx.x;   // grid 96 -> 24576
    rowPk[idx] = 0ull; colPk[idx] = 0ull;
    rowSm[idx] = 0.f;  colSm[idx] = 0.f;
    if (idx < 16) { sq[idx] = 0.f; cnt[idx] = 0; }
}

// ---- sim (r10 structure): 64x64 tile, split-bf16 3-term, exp-once, fp8 E/ET,
//      atomic-published row/col stats. grid (64, 64, 3 pairs) ----
__global__ __launch_bounds__(256) void sim_mfma_k(
    const unsigned short* __restrict__ dnh, const unsigned short* __restrict__ dnl,
    int ipack, int jpack, unsigned char* __restrict__ E8b, unsigned char* __restrict__ ET8b,
    u64* __restrict__ rowPkB, float* __restrict__ rowSmB,
    u64* __restrict__ colPkB, float* __restrict__ colSmB, int slotBase) {
    __shared__ unsigned char smem[36864];
    __shared__ float sRedM[256];
    __shared__ int   sRedA[256];
    __shared__ float sRedS[256];
    unsigned short* sAh = (unsigned short*)smem;          // [64][72]
    unsigned short* sAl = sAh + 64 * 72;
    unsigned short* sBh = sAl + 64 * 72;
    unsigned short* sBl = sBh + 64 * 72;
    float* S = (float*)smem;                               // [64][65] alias, holds expS

    int zp = blockIdx.z;
    int iv = (ipack >> (8 * zp)) & 15;
    int jv = (jpack >> (8 * zp)) & 15;
    const unsigned short* Ahi = dnh + (size_t)iv * N_ * C_;
    const unsigned short* Alo = dnl + (size_t)iv * N_ * C_;
    const unsigned short* Bhi = dnh + (size_t)jv * N_ * C_;
    const unsigned short* Blo = dnl + (size_t)jv * N_ * C_;
    unsigned char* E8  = E8b  + (size_t)zp * N_ * N_;
    unsigned char* ET8 = ET8b + (size_t)zp * N_ * N_;
    int slot = slotBase + zp;
    u64*   rowPk = rowPkB + (size_t)slot * N_;
    float* rowSm = rowSmB + (size_t)slot * N_;
    u64*   colPk = colPkB + (size_t)slot * N_;
    float* colSm = colSmB + (size_t)slot * N_;

    int tid = threadIdx.x;
    int m0 = blockIdx.y * 64, n0 = blockIdx.x * 64;
    int w = tid >> 6, l = tid & 63;
    int wm = w & 1, wn = w >> 1;
    int mr = l & 15, q = l >> 4;

    f32x4 acc[2][2];
#pragma unroll
    for (int a = 0; a < 2; ++a)
#pragma unroll
        for (int b = 0; b < 2; ++b)
#pragma unroll
            for (int u = 0; u < 4; ++u) acc[a][b][u] = 0.f;

    int r = tid >> 2;
    int k8 = (tid & 3) * 8;

    for (int k0 = 0; k0 < C_; k0 += 64) {
        size_t ga = (size_t)(m0 + r) * C_ + k0 + k8;
        size_t gb = (size_t)(n0 + r) * C_ + k0 + k8;
        uint4 a0 = *(const uint4*)(Ahi + ga);
        uint4 a1 = *(const uint4*)(Ahi + ga + 32);
        uint4 a2 = *(const uint4*)(Alo + ga);
        uint4 a3 = *(const uint4*)(Alo + ga + 32);
        uint4 b0 = *(const uint4*)(Bhi + gb);
        uint4 b1 = *(const uint4*)(Bhi + gb + 32);
        uint4 b2 = *(const uint4*)(Blo + gb);
        uint4 b3 = *(const uint4*)(Blo + gb + 32);
        *(uint4*)(sAh + r * 72 + k8)      = a0;
        *(uint4*)(sAh + r * 72 + k8 + 32) = a1;
        *(uint4*)(sAl + r * 72 + k8)      = a2;
        *(uint4*)(sAl + r * 72 + k8 + 32) = a3;
        *(uint4*)(sBh + r * 72 + k8)      = b0;
        *(uint4*)(sBh + r * 72 + k8 + 32) = b1;
        *(uint4*)(sBl + r * 72 + k8)      = b2;
        *(uint4*)(sBl + r * 72 + k8 + 32) = b3;
        __syncthreads();
#pragma unroll
        for (int ks = 0; ks < 64; ks += 32) {
            bf16x8 ah[2], al[2], bh[2], bl[2];
#pragma unroll
            for (int ti = 0; ti < 2; ++ti) {
                int mrow = wm * 32 + ti * 16 + mr;
                ah[ti] = *(const bf16x8*)(sAh + mrow * 72 + ks + q * 8);
                al[ti] = *(const bf16x8*)(sAl + mrow * 72 + ks + q * 8);
            }
#pragma unroll
            for (int tj = 0; tj < 2; ++tj) {
                int nrow = wn * 32 + tj * 16 + mr;
                bh[tj] = *(const bf16x8*)(sBh + nrow * 72 + ks + q * 8);
                bl[tj] = *(const bf16x8*)(sBl + nrow * 72 + ks + q * 8);
            }
#pragma unroll
            for (int ti = 0; ti < 2; ++ti)
#pragma unroll
                for (int tj = 0; tj < 2; ++tj) {
                    acc[ti][tj] = mfma16(ah[ti], bh[tj], acc[ti][tj]);
                    acc[ti][tj] = mfma16(ah[ti], bl[tj], acc[ti][tj]);
                    acc[ti][tj] = mfma16(al[ti], bh[tj], acc[ti][tj]);
                }
        }
        __syncthreads();
    }

    // ---- epilogue: exp once into LDS (monotone -> argmax/sum equivalent) ----
#pragma unroll
    for (int ti = 0; ti < 2; ++ti)
#pragma unroll
        for (int tj = 0; tj < 2; ++tj)
#pragma unroll
            for (int rg = 0; rg < 4; ++rg)
                S[(wm * 32 + ti * 16 + q * 4 + rg) * 65 + wn * 32 + tj * 16 + mr] =
                    __expf(acc[ti][tj][rg]);
    __syncthreads();

    // row stats -> atomics
    {
        int rr = tid >> 2, q4 = tid & 3;
        float mx = -1e30f; int ag = 0; float sm = 0.f;
        for (int cc = 0; cc < 16; ++cc) {
            int c = q4 * 16 + cc;
            float v = S[rr * 65 + c];
            sm += v;
            if (v > mx) { mx = v; ag = c; }
        }
        sRedM[tid] = mx; sRedA[tid] = ag; sRedS[tid] = sm;
    }
    __syncthreads();
    if (tid < 64) {
        float mx = -1e30f; int ag = 0; float sm = 0.f;
        for (int qq = 0; qq < 4; ++qq) {
            float v = sRedM[tid * 4 + qq];
            if (v > mx) { mx = v; ag = sRedA[tid * 4 + qq]; }
            sm += sRedS[tid * 4 + qq];
        }
        u64 pk = ((u64)__float_as_uint(mx) << 32) | (u64)(0xFFFFFFFFu - (unsigned)(n0 + ag));
        atomicMax(rowPk + m0 + tid, pk);
        atomicAdd(rowSm + m0 + tid, sm);
    }
    __syncthreads();
    // col stats -> atomics
    {
        int cc = tid >> 2, q4 = tid & 3;
        float mx = -1e30f; int ag = 0; float sm = 0.f;
        for (int rr = 0; rr < 16; ++rr) {
            int rrr = q4 * 16 + rr;
            float v = S[rrr * 65 + cc];
            sm += v;
            if (v > mx) { mx = v; ag = rrr; }
        }
        sRedM[tid] = mx; sRedA[tid] = ag; sRedS[tid] = sm;
    }
    __syncthreads();
    if (tid < 64) {
        float mx = -1e30f; int ag = 0; float sm = 0.f;
        for (int qq = 0; qq < 4; ++qq) {
            float v = sRedM[tid * 4 + qq];
            if (v > mx) { mx = v; ag = sRedA[tid * 4 + qq]; }
            sm += sRedS[tid * 4 + qq];
        }
        u64 pk = ((u64)__float_as_uint(mx) << 32) | (u64)(0xFFFFFFFFu - (unsigned)(m0 + ag));
        atomicMax(colPk + n0 + tid, pk);
        atomicAdd(colSm + n0 + tid, sm);
    }
    // E store (fp8), row-major
    {
        int r2 = tid >> 2, cq = (tid & 3) * 16;
        unsigned int wb[4];
#pragma unroll
        for (int g = 0; g < 4; ++g) {
            const float* p = S + r2 * 65 + cq + g * 4;
            wb[g] = pk4fp8(p[0], p[1], p[2], p[3]);
        }
        *(uint4*)(E8 + (size_t)(m0 + r2) * N_ + n0 + cq) = make_uint4(wb[0], wb[1], wb[2], wb[3]);
    }
    // ET store (fp8), row-major in n
    {
        int n2 = tid >> 2, mq = (tid & 3) * 16;
        unsigned int wb[4];
#pragma unroll
        for (int g = 0; g < 4; ++g) {
            wb[g] = pk4fp8(S[(mq + g * 4 + 0) * 65 + n2], S[(mq + g * 4 + 1) * 65 + n2],
                           S[(mq + g * 4 + 2) * 65 + n2], S[(mq + g * 4 + 3) * 65 + n2]);
        }
        *(uint4*)(ET8 + (size_t)(n0 + n2) * N_ + m0 + mq) = make_uint4(wb[0], wb[1], wb[2], wb[3]);
    }
}

// ---- pass2: fp8 GEMM (32m x 64c, K=4096) + fused loss; grid (1024, 3 pairs) ----
__global__ __launch_bounds__(256) void p2_k(
    const unsigned char* __restrict__ E8b, const unsigned char* __restrict__ ET8b,
    const unsigned char* __restrict__ sf8T, int ipack, int jpack,
    const u64* __restrict__ rowPkB, const float* __restrict__ rowSmB,
    const u64* __restrict__ colPkB, const float* __restrict__ colSmB, int slotBase,
    const float* __restrict__ R, const float* __restrict__ relwt,
    float* __restrict__ pairSq, int* __restrict__ pairCnt) {
    __shared__ unsigned char sA[32 * 144];
    __shared__ unsigned char sB[64 * 144];
    __shared__ float red[256];
    __shared__ int   mutS[32];
    __shared__ float invS[32];
    int tid = threadIdx.x;
    int zp = blockIdx.y;
    int iv = (ipack >> (8 * zp)) & 15;
    int jv = (jpack >> (8 * zp)) & 15;
    int slot = slotBase + zp;
    int lin = blockIdx.x;
    int xcd = lin & 7, slotx = lin >> 3;
    int grp = xcd + 8 * (slotx >> 2);
    int ct = slotx & 3;
    int mt = grp & 127, d = grp >> 7;
    const unsigned char* A = (d ? ET8b : E8b) + (size_t)zp * N_ * N_;
    const unsigned char* B = sf8T + (size_t)(d ? iv : jv) * C_ * N_;
    const u64* faPk = (d ? colPkB : rowPkB) + (size_t)slot * N_;
    const u64* baPk = (d ? rowPkB : colPkB) + (size_t)slot * N_;
    const float* sumE = (d ? colSmB : rowSmB) + (size_t)slot * N_;
    const float* Rr = R + (size_t)(d ? jv : iv) * N_ * C_;
    int pid = d ? (jv * 4 + iv) : (iv * 4 + jv);
    int c0 = ct * 64, m0 = mt * 32;
    int w = tid >> 6, l = tid & 63, wm = w & 1, wn = w >> 1;
    int mr = l & 15, q = l >> 4;
    if (tid < 32) {
        int y = m0 + tid;
        unsigned faIdx = 0xFFFFFFFFu - (unsigned)(faPk[y] & 0xFFFFFFFFull);
        unsigned baIdx = 0xFFFFFFFFu - (unsigned)(baPk[faIdx] & 0xFFFFFFFFull);
        mutS[tid] = (baIdx == (unsigned)y) ? 1 : 0;
        invS[tid] = 1.0f / sumE[y];
    }
    f32x4 acc[2];
#pragma unroll
    for (int b = 0; b < 2; ++b)
#pragma unroll
        for (int u = 0; u < 4; ++u) acc[b][u] = 0.f;

    int ra = tid >> 3, ka = (tid & 7) * 16;
    int rb = tid >> 2, kb = (tid & 3) * 32;
    const unsigned char* Arow = A + (size_t)(m0 + ra) * N_;
    const unsigned char* Brow = B + (size_t)(c0 + rb) * N_;
    uint4 pa  = *(const uint4*)(Arow + ka);
    uint4 pb0 = *(const uint4*)(Brow + kb);
    uint4 pb1 = *(const uint4*)(Brow + kb + 16);
    for (int k0 = 0; k0 < N_; k0 += 128) {
        *(uint4*)(sA + ra * 144 + ka)      = pa;
        *(uint4*)(sB + rb * 144 + kb)      = pb0;
        *(uint4*)(sB + rb * 144 + kb + 16) = pb1;
        __syncthreads();
        int kn = k0 + 128;
        if (kn < N_) {
            pa  = *(const uint4*)(Arow + kn + ka);
            pb0 = *(const uint4*)(Brow + kn + kb);
            pb1 = *(const uint4*)(Brow + kn + kb + 16);
        }
#pragma unroll
        for (int ksub = 0; ksub < 128; ksub += 32) {
            long af = *(const long*)(sA + (wm * 16 + mr) * 144 + ksub + q * 8);
            long b0 = *(const long*)(sB + (wn * 32 + mr) * 144 + ksub + q * 8);
            long b1 = *(const long*)(sB + (wn * 32 + 16 + mr) * 144 + ksub + q * 8);
            acc[0] = __builtin_amdgcn_mfma_f32_16x16x32_fp8_fp8(af, b0, acc[0], 0, 0, 0);
            acc[1] = __builtin_amdgcn_mfma_f32_16x16x32_fp8_fp8(af, b1, acc[1], 0, 0, 0);
        }
        __syncthreads();
    }
    const float* rw = relwt + (size_t)pid * C_;
    float local = 0.f;
#pragma unroll
    for (int tj = 0; tj < 2; ++tj) {
        int c = c0 + wn * 32 + tj * 16 + mr;
        float rwc = rw[c];
#pragma unroll
        for (int rg = 0; rg < 4; ++rg) {
            int ml = wm * 16 + q * 4 + rg;
            if (mutS[ml]) {
                int m = m0 + ml;
                float soft = acc[tj][rg] * invS[ml];
                float dv = Rr[(size_t)m * C_ + c] + rwc - soft;
                local += dv * dv;
            }
        }
    }
    red[tid] = local;
    __syncthreads();
    for (int s = 128; s > 0; s >>= 1) {
        if (tid < s) red[tid] += red[tid + s];
        __syncthreads();
    }
    if (tid == 0) {
        atomicAdd(pairSq + pid, red[0]);
        if (ct == 0) {
            int cnt = 0;
            for (int u = 0; u < 32; ++u) cnt += mutS[u];
            atomicAdd(pairCnt + pid, cnt);
        }
    }
}

// ---- final scalar combine ----
__global__ void final_k(const float* __restrict__ sq, const int* __restrict__ cnt,
                        float* __restrict__ out) {
    if (threadIdx.x == 0 && blockIdx.x == 0) {
        float loss = 0.f, count = 0.f;
        for (int p = 0; p < 16; ++p) {
            int i = p >> 2, j = p & 3;
            if (i == j) continue;
            float ns = (float)cnt[p];
            if (ns > 0.f) { loss += sq[p] / fmaxf(ns * (float)C_, 1.0f); count += 1.f; }
        }
        out[0] = (count > 0.f) ? loss / count : 0.f;
    }
}

extern "C" void kernel_launch(void* const* d_in, const int* in_sizes, int n_in,
                              void* d_out, int out_size, void* d_ws, size_t ws_size,
                              hipStream_t stream) {
    const float* desc = (const float*)d_in[0];
    const float* sf   = (const float*)d_in[1];
    const float* T    = (const float*)d_in[2];
    const float* Wrec = (const float*)d_in[3];
    const float* WT   = (const float*)d_in[4];
    float* out = (float*)d_out;
    char* ws = (char*)d_ws;

    float*          R     = (float*)(ws + OFF_R);
    unsigned short* dnh   = (unsigned short*)(ws + OFF_DNHI);
    unsigned short* dnl   = (unsigned short*)(ws + OFF_DNLO);
    unsigned char*  sf8T  = (unsigned char*)(ws + OFF_SFT);
    unsigned char*  E8b   = (unsigned char*)(ws + OFF_E);
    unsigned char*  ET8b  = (unsigned char*)(ws + OFF_ET);
    unsigned short* WTh   = (unsigned short*)(ws + OFF_WTH);
    unsigned short* WTl   = (unsigned short*)(ws + OFF_WTL);
    u64*   rowPk = (u64*)(ws + OFF_ROWPK);
    u64*   colPk = (u64*)(ws + OFF_COLPK);
    float* rowSm = (float*)(ws + OFF_ROWSM);
    float* colSm = (float*)(ws + OFF_COLSM);
    float* relwt = (float*)(ws + OFF_RELWT);
    float* pairSq = (float*)(ws + OFF_SQ);
    int*   pairCnt = (int*)(ws + OFF_CNT);

    normalize_k<<<N_ * V_, 256, 0, stream>>>(desc, dnh, dnl);
    wrecT_k<<<dim3(4, 4), 256, 0, stream>>>(Wrec, WTh, WTl);
    rmatmul_k<<<dim3(2, 128), 256, 0, stream>>>(dnh, dnl, WTh, WTl, R);
    sfT_k<<<dim3(64, 4, 4), 256, 0, stream>>>(sf, sf8T);
    relwt_k<<<16, 256, 0, stream>>>(T, WT, relwt);
    zero_k<<<96, 256, 0, stream>>>(rowPk, colPk, rowSm, colSm, pairSq, pairCnt);

    // batch 0: pairs (0,1),(0,2),(0,3); batch 1: (1,2),(1,3),(2,3)
    const int ip[2] = { 0 | (0 << 8) | (0 << 16), 1 | (1 << 8) | (2 << 16) };
    const int jp[2] = { 1 | (2 << 8) | (3 << 16), 2 | (3 << 8) | (3 << 16) };
    for (int b = 0; b < 2; ++b) {
        sim_mfma_k<<<dim3(64, 64, 3), 256, 0, stream>>>(
            dnh, dnl, ip[b], jp[b], E8b, ET8b, rowPk, rowSm, colPk, colSm, b * 3);
        p2_k<<<dim3(1024, 3), 256, 0, stream>>>(
            E8b, ET8b, sf8T, ip[b], jp[b], rowPk, rowSm, colPk, colSm, b * 3,
            R, relwt, pairSq, pairCnt);
    }
    final_k<<<1, 64, 0, stream>>>(pairSq, pairCnt, out);
}

// Round 13
// 511.136 us; speedup vs baseline: 2.1268x; 1.1009x over previous
//
#include <hip/hip_runtime.h>
#include <math.h>

#define N_ 4096
#define V_ 4
#define C_ 256

typedef __attribute__((ext_vector_type(8))) short bf16x8;
typedef __attribute__((ext_vector_type(4))) float f32x4;
typedef unsigned long long u64;

// ---------------- workspace byte offsets ----------------
#define OFF_R      0ull            // f32 R[v][n][c]          16MB
#define OFF_DNHI   16777216ull     // bf16                     8MB
#define OFF_DNLO   25165824ull     // bf16                     8MB
#define OFF_SFT    33554432ull     // fp8 sfT[v][c][n]         4MB
#define OFF_E      37748736ull     // fp8 E slots x3          48MB
#define OFF_ET     88080384ull     // fp8 ET slots x3         48MB
#define OFF_WTH    138412032ull    // bf16 WT hi 256x256     128KB
#define OFF_WTL    138543104ull
#define OFF_ROWPK  138674176ull    // u64 rowPk[6][4096]     192KB
#define OFF_COLPK  138870784ull    // u64 colPk[6][4096]
#define OFF_ROWSM  139067392ull    // f32 rowSm[6][4096]      96KB
#define OFF_COLSM  139165696ull
#define OFF_RELWT  139264000ull    // f32 16x256
#define OFF_SQ     139280384ull
#define OFF_CNT    139280448ull

__device__ __forceinline__ unsigned short f2bf(float x) {
    unsigned int u = __float_as_uint(x);
    u += 0x7fffu + ((u >> 16) & 1u);
    return (unsigned short)(u >> 16);
}
__device__ __forceinline__ float bf2f(unsigned short h) {
    return __uint_as_float(((unsigned int)h) << 16);
}
__device__ __forceinline__ f32x4 mfma16(bf16x8 a, bf16x8 b, f32x4 c) {
    return __builtin_amdgcn_mfma_f32_16x16x32_bf16(a, b, c, 0, 0, 0);
}
__device__ __forceinline__ unsigned int pk4fp8(float x0, float x1, float x2, float x3) {
    int w = 0;
    w = __builtin_amdgcn_cvt_pk_fp8_f32(x0, x1, w, false);
    w = __builtin_amdgcn_cvt_pk_fp8_f32(x2, x3, w, true);
    return (unsigned int)w;
}

// ---- normalize + bf16 hi/lo split: dn[v][n][c] ----
__global__ void normalize_k(const float* __restrict__ desc,
                            unsigned short* __restrict__ dnh, unsigned short* __restrict__ dnl) {
    int row = blockIdx.x;            // n*V + v
    int n = row >> 2, v = row & 3;
    int c = threadIdx.x;
    float x = desc[(size_t)row * C_ + c];
    __shared__ float red[256];
    red[c] = x * x;
    __syncthreads();
    for (int s = 128; s > 0; s >>= 1) {
        if (c < s) red[c] += red[c + s];
        __syncthreads();
    }
    float inv = 1.0f / fmaxf(sqrtf(red[0]), 1e-12f);
    float y = x * inv;
    size_t o = ((size_t)v * N_ + n) * C_ + c;
    unsigned short h = f2bf(y);
    dnh[o] = h;
    dnl[o] = f2bf(y - bf2f(h));
}

// ---- WT[c][k] = W_rec[k][c], hi/lo bf16 split ----
__global__ void wrecT_k(const float* __restrict__ W, unsigned short* __restrict__ WTh,
                        unsigned short* __restrict__ WTl) {
    __shared__ float Tt[64 * 65];
    int k0 = blockIdx.x * 64, c0 = blockIdx.y * 64;
    int t = threadIdx.x;
    int kr = t >> 2, cq = (t & 3) * 16;
    const float* src = W + (size_t)(k0 + kr) * C_ + c0 + cq;
    for (int u = 0; u < 16; ++u) Tt[(cq + u) * 65 + kr] = src[u];
    __syncthreads();
    int cr = t >> 2, kq = (t & 3) * 16;
    unsigned short th[16] __attribute__((aligned(16)));
    unsigned short tl[16] __attribute__((aligned(16)));
    for (int u = 0; u < 16; ++u) {
        float x = Tt[cr * 65 + kq + u];
        unsigned short h = f2bf(x);
        th[u] = h; tl[u] = f2bf(x - bf2f(h));
    }
    size_t o = (size_t)(c0 + cr) * C_ + k0 + kq;
    *(uint4*)(WTh + o) = *(const uint4*)th;
    *(uint4*)(WTh + o + 8) = *(const uint4*)(th + 8);
    *(uint4*)(WTl + o) = *(const uint4*)tl;
    *(uint4*)(WTl + o + 8) = *(const uint4*)(tl + 8);
}

// ---- R = dn @ W_rec via split-bf16 MFMA; block 128x128, wave 64x64 ----
__global__ __launch_bounds__(256) void rmatmul_k(
    const unsigned short* __restrict__ Ah, const unsigned short* __restrict__ Al,
    const unsigned short* __restrict__ Bh, const unsigned short* __restrict__ Bl,
    float* __restrict__ R) {
    __shared__ unsigned short smem[4 * 128 * 40];
    unsigned short* sAh = smem;
    unsigned short* sAl = sAh + 128 * 40;
    unsigned short* sBh = sAl + 128 * 40;
    unsigned short* sBl = sBh + 128 * 40;
    int tid = threadIdx.x;
    int c0 = blockIdx.x * 128, m0 = blockIdx.y * 128;
    int w = tid >> 6, l = tid & 63, wm = w & 1, wn = w >> 1;
    int mr = l & 15, q = l >> 4;
    f32x4 acc[4][4];
#pragma unroll
    for (int a = 0; a < 4; ++a)
#pragma unroll
        for (int b = 0; b < 4; ++b)
#pragma unroll
            for (int u = 0; u < 4; ++u) acc[a][b][u] = 0.f;
    int r = tid >> 1, h = (tid & 1) * 16;
    for (int k0 = 0; k0 < C_; k0 += 32) {
        size_t ga = (size_t)(m0 + r) * C_ + k0 + h;
        size_t gb = (size_t)(c0 + r) * C_ + k0 + h;
        uint4 a0 = *(const uint4*)(Ah + ga);
        uint4 a1 = *(const uint4*)(Ah + ga + 8);
        uint4 a2 = *(const uint4*)(Al + ga);
        uint4 a3 = *(const uint4*)(Al + ga + 8);
        uint4 b0 = *(const uint4*)(Bh + gb);
        uint4 b1 = *(const uint4*)(Bh + gb + 8);
        uint4 b2 = *(const uint4*)(Bl + gb);
        uint4 b3 = *(const uint4*)(Bl + gb + 8);
        *(uint4*)(sAh + r * 40 + h)     = a0;
        *(uint4*)(sAh + r * 40 + h + 8) = a1;
        *(uint4*)(sAl + r * 40 + h)     = a2;
        *(uint4*)(sAl + r * 40 + h + 8) = a3;
        *(uint4*)(sBh + r * 40 + h)     = b0;
        *(uint4*)(sBh + r * 40 + h + 8) = b1;
        *(uint4*)(sBl + r * 40 + h)     = b2;
        *(uint4*)(sBl + r * 40 + h + 8) = b3;
        __syncthreads();
        bf16x8 fah[4], fal[4], fbh[4], fbl[4];
#pragma unroll
        for (int ti = 0; ti < 4; ++ti) {
            int row = wm * 64 + ti * 16 + mr;
            fah[ti] = *(const bf16x8*)(sAh + row * 40 + q * 8);
            fal[ti] = *(const bf16x8*)(sAl + row * 40 + q * 8);
        }
#pragma unroll
        for (int tj = 0; tj < 4; ++tj) {
            int row = wn * 64 + tj * 16 + mr;
            fbh[tj] = *(const bf16x8*)(sBh + row * 40 + q * 8);
            fbl[tj] = *(const bf16x8*)(sBl + row * 40 + q * 8);
        }
#pragma unroll
        for (int ti = 0; ti < 4; ++ti)
#pragma unroll
            for (int tj = 0; tj < 4; ++tj) acc[ti][tj] = mfma16(fah[ti], fbh[tj], acc[ti][tj]);
#pragma unroll
        for (int ti = 0; ti < 4; ++ti)
#pragma unroll
            for (int tj = 0; tj < 4; ++tj) acc[ti][tj] = mfma16(fah[ti], fbl[tj], acc[ti][tj]);
#pragma unroll
        for (int ti = 0; ti < 4; ++ti)
#pragma unroll
            for (int tj = 0; tj < 4; ++tj) acc[ti][tj] = mfma16(fal[ti], fbh[tj], acc[ti][tj]);
        __syncthreads();
    }
#pragma unroll
    for (int ti = 0; ti < 4; ++ti)
#pragma unroll
        for (int tj = 0; tj < 4; ++tj) {
            int c = c0 + wn * 64 + tj * 16 + mr;
#pragma unroll
            for (int rg = 0; rg < 4; ++rg) {
                int m = m0 + wm * 64 + ti * 16 + q * 4 + rg;
                R[(size_t)m * C_ + c] = acc[ti][tj][rg];
            }
        }
}

// ---- relWT[p][c], p = i*4+j ----
__global__ void relwt_k(const float* __restrict__ T, const float* __restrict__ WT,
                        float* __restrict__ relwt) {
    int p = blockIdx.x; int i = p >> 2, j = p & 3;
    if (i == j) return;
    int c = threadIdx.x;
    float acc = 0.f;
    for (int k = 0; k < 16; ++k) acc += T[i * 16 + k] * WT[(size_t)k * C_ + c];
    for (int k = 0; k < 16; ++k) acc += T[j * 16 + k] * WT[(size_t)(16 + k) * C_ + c];
    relwt[(size_t)p * C_ + c] = acc;
}

// ---- sf8T[v][c][n] = fp8(sf[n][v][c]) ----
__global__ void sfT_k(const float* __restrict__ sf, unsigned char* __restrict__ sf8T) {
    __shared__ float Tt[64 * 65];
    int n0 = blockIdx.x * 64, c0 = blockIdx.y * 64, v = blockIdx.z;
    int t = threadIdx.x;
    int nr = t >> 2, cq = (t & 3) * 16;
    const float* src = sf + ((size_t)(n0 + nr) * V_ + v) * C_ + c0 + cq;
    for (int u = 0; u < 16; ++u) Tt[(cq + u) * 65 + nr] = src[u];
    __syncthreads();
    int cr = t >> 2, nq = (t & 3) * 16;
    unsigned int wb[4];
#pragma unroll
    for (int g = 0; g < 4; ++g) {
        const float* p = Tt + cr * 65 + nq + g * 4;
        wb[g] = pk4fp8(p[0], p[1], p[2], p[3]);
    }
    unsigned char* dst = sf8T + ((size_t)v * C_ + c0 + cr) * N_ + n0 + nq;
    *(uint4*)dst = make_uint4(wb[0], wb[1], wb[2], wb[3]);
}

// ---- zero stats (all 6 slots) + pair accumulators ----
__global__ void zero_k(u64* rowPk, u64* colPk, float* rowSm, float* colSm,
                       float* sq, int* cnt) {
    int idx = blockIdx.x * 256 + threadIdx.x;   // grid 96 -> 24576
    rowPk[idx] = 0ull; colPk[idx] = 0ull;
    rowSm[idx] = 0.f;  colSm[idx] = 0.f;
    if (idx < 16) { sq[idx] = 0.f; cnt[idx] = 0; }
}

// ---- sim: 64x64 tile, split-bf16 3-term, exp-once, fp8 E/ET, atomic stats ----
__global__ __launch_bounds__(256) void sim_mfma_k(
    const unsigned short* __restrict__ dnh, const unsigned short* __restrict__ dnl,
    int ipack, int jpack, unsigned char* __restrict__ E8b, unsigned char* __restrict__ ET8b,
    u64* __restrict__ rowPkB, float* __restrict__ rowSmB,
    u64* __restrict__ colPkB, float* __restrict__ colSmB, int slotBase) {
    __shared__ unsigned char smem[36864];
    __shared__ float sRedM[256];
    __shared__ int   sRedA[256];
    __shared__ float sRedS[256];
    unsigned short* sAh = (unsigned short*)smem;          // [64][72]
    unsigned short* sAl = sAh + 64 * 72;
    unsigned short* sBh = sAl + 64 * 72;
    unsigned short* sBl = sBh + 64 * 72;
    float* S = (float*)smem;                               // [64][65] alias, holds expS

    int zp = blockIdx.z;
    int iv = (ipack >> (8 * zp)) & 15;
    int jv = (jpack >> (8 * zp)) & 15;
    const unsigned short* Ahi = dnh + (size_t)iv * N_ * C_;
    const unsigned short* Alo = dnl + (size_t)iv * N_ * C_;
    const unsigned short* Bhi = dnh + (size_t)jv * N_ * C_;
    const unsigned short* Blo = dnl + (size_t)jv * N_ * C_;
    unsigned char* E8  = E8b  + (size_t)zp * N_ * N_;
    unsigned char* ET8 = ET8b + (size_t)zp * N_ * N_;
    int slot = slotBase + zp;
    u64*   rowPk = rowPkB + (size_t)slot * N_;
    float* rowSm = rowSmB + (size_t)slot * N_;
    u64*   colPk = colPkB + (size_t)slot * N_;
    float* colSm = colSmB + (size_t)slot * N_;

    int tid = threadIdx.x;
    int m0 = blockIdx.y * 64, n0 = blockIdx.x * 64;
    int w = tid >> 6, l = tid & 63;
    int wm = w & 1, wn = w >> 1;
    int mr = l & 15, q = l >> 4;

    f32x4 acc[2][2];
#pragma unroll
    for (int a = 0; a < 2; ++a)
#pragma unroll
        for (int b = 0; b < 2; ++b)
#pragma unroll
            for (int u = 0; u < 4; ++u) acc[a][b][u] = 0.f;

    int r = tid >> 2;
    int k8 = (tid & 3) * 8;

    for (int k0 = 0; k0 < C_; k0 += 64) {
        size_t ga = (size_t)(m0 + r) * C_ + k0 + k8;
        size_t gb = (size_t)(n0 + r) * C_ + k0 + k8;
        uint4 a0 = *(const uint4*)(Ahi + ga);
        uint4 a1 = *(const uint4*)(Ahi + ga + 32);
        uint4 a2 = *(const uint4*)(Alo + ga);
        uint4 a3 = *(const uint4*)(Alo + ga + 32);
        uint4 b0 = *(const uint4*)(Bhi + gb);
        uint4 b1 = *(const uint4*)(Bhi + gb + 32);
        uint4 b2 = *(const uint4*)(Blo + gb);
        uint4 b3 = *(const uint4*)(Blo + gb + 32);
        *(uint4*)(sAh + r * 72 + k8)      = a0;
        *(uint4*)(sAh + r * 72 + k8 + 32) = a1;
        *(uint4*)(sAl + r * 72 + k8)      = a2;
        *(uint4*)(sAl + r * 72 + k8 + 32) = a3;
        *(uint4*)(sBh + r * 72 + k8)      = b0;
        *(uint4*)(sBh + r * 72 + k8 + 32) = b1;
        *(uint4*)(sBl + r * 72 + k8)      = b2;
        *(uint4*)(sBl + r * 72 + k8 + 32) = b3;
        __syncthreads();
#pragma unroll
        for (int ks = 0; ks < 64; ks += 32) {
            bf16x8 ah[2], al[2], bh[2], bl[2];
#pragma unroll
            for (int ti = 0; ti < 2; ++ti) {
                int mrow = wm * 32 + ti * 16 + mr;
                ah[ti] = *(const bf16x8*)(sAh + mrow * 72 + ks + q * 8);
                al[ti] = *(const bf16x8*)(sAl + mrow * 72 + ks + q * 8);
            }
#pragma unroll
            for (int tj = 0; tj < 2; ++tj) {
                int nrow = wn * 32 + tj * 16 + mr;
                bh[tj] = *(const bf16x8*)(sBh + nrow * 72 + ks + q * 8);
                bl[tj] = *(const bf16x8*)(sBl + nrow * 72 + ks + q * 8);
            }
#pragma unroll
            for (int ti = 0; ti < 2; ++ti)
#pragma unroll
                for (int tj = 0; tj < 2; ++tj) {
                    acc[ti][tj] = mfma16(ah[ti], bh[tj], acc[ti][tj]);
                    acc[ti][tj] = mfma16(ah[ti], bl[tj], acc[ti][tj]);
                    acc[ti][tj] = mfma16(al[ti], bh[tj], acc[ti][tj]);
                }
        }
        __syncthreads();
    }

    // ---- epilogue: exp once into LDS ----
#pragma unroll
    for (int ti = 0; ti < 2; ++ti)
#pragma unroll
        for (int tj = 0; tj < 2; ++tj)
#pragma unroll
            for (int rg = 0; rg < 4; ++rg)
                S[(wm * 32 + ti * 16 + q * 4 + rg) * 65 + wn * 32 + tj * 16 + mr] =
                    __expf(acc[ti][tj][rg]);
    __syncthreads();

    // row stats -> atomics
    {
        int rr = tid >> 2, q4 = tid & 3;
        float mx = -1e30f; int ag = 0; float sm = 0.f;
        for (int cc = 0; cc < 16; ++cc) {
            int c = q4 * 16 + cc;
            float v = S[rr * 65 + c];
            sm += v;
            if (v > mx) { mx = v; ag = c; }
        }
        sRedM[tid] = mx; sRedA[tid] = ag; sRedS[tid] = sm;
    }
    __syncthreads();
    if (tid < 64) {
        float mx = -1e30f; int ag = 0; float sm = 0.f;
        for (int qq = 0; qq < 4; ++qq) {
            float v = sRedM[tid * 4 + qq];
            if (v > mx) { mx = v; ag = sRedA[tid * 4 + qq]; }
            sm += sRedS[tid * 4 + qq];
        }
        u64 pk = ((u64)__float_as_uint(mx) << 32) | (u64)(0xFFFFFFFFu - (unsigned)(n0 + ag));
        atomicMax(rowPk + m0 + tid, pk);
        atomicAdd(rowSm + m0 + tid, sm);
    }
    __syncthreads();
    // col stats -> atomics
    {
        int cc = tid >> 2, q4 = tid & 3;
        float mx = -1e30f; int ag = 0; float sm = 0.f;
        for (int rr = 0; rr < 16; ++rr) {
            int rrr = q4 * 16 + rr;
            float v = S[rrr * 65 + cc];
            sm += v;
            if (v > mx) { mx = v; ag = rrr; }
        }
        sRedM[tid] = mx; sRedA[tid] = ag; sRedS[tid] = sm;
    }
    __syncthreads();
    if (tid < 64) {
        float mx = -1e30f; int ag = 0; float sm = 0.f;
        for (int qq = 0; qq < 4; ++qq) {
            float v = sRedM[tid * 4 + qq];
            if (v > mx) { mx = v; ag = sRedA[tid * 4 + qq]; }
            sm += sRedS[tid * 4 + qq];
        }
        u64 pk = ((u64)__float_as_uint(mx) << 32) | (u64)(0xFFFFFFFFu - (unsigned)(m0 + ag));
        atomicMax(colPk + n0 + tid, pk);
        atomicAdd(colSm + n0 + tid, sm);
    }
    // E store (fp8), row-major
    {
        int r2 = tid >> 2, cq = (tid & 3) * 16;
        unsigned int wb[4];
#pragma unroll
        for (int g = 0; g < 4; ++g) {
            const float* p = S + r2 * 65 + cq + g * 4;
            wb[g] = pk4fp8(p[0], p[1], p[2], p[3]);
        }
        *(uint4*)(E8 + (size_t)(m0 + r2) * N_ + n0 + cq) = make_uint4(wb[0], wb[1], wb[2], wb[3]);
    }
    // ET store (fp8), row-major in n
    {
        int n2 = tid >> 2, mq = (tid & 3) * 16;
        unsigned int wb[4];
#pragma unroll
        for (int g = 0; g < 4; ++g) {
            wb[g] = pk4fp8(S[(mq + g * 4 + 0) * 65 + n2], S[(mq + g * 4 + 1) * 65 + n2],
                           S[(mq + g * 4 + 2) * 65 + n2], S[(mq + g * 4 + 3) * 65 + n2]);
        }
        *(uint4*)(ET8 + (size_t)(n0 + n2) * N_ + m0 + mq) = make_uint4(wb[0], wb[1], wb[2], wb[3]);
    }
}

// ---- pass2 v3: fp8 GEMM 64m x 128c, K-chunk 64, pitch-80 LDS, fused loss ----
// grid: (128, 6): bx -> ct = bx&1 (c half), mt = bx>>1; by -> d = by&1, zp = by>>1
__global__ __launch_bounds__(256) void p2_k(
    const unsigned char* __restrict__ E8b, const unsigned char* __restrict__ ET8b,
    const unsigned char* __restrict__ sf8T, int ipack, int jpack,
    const u64* __restrict__ rowPkB, const float* __restrict__ rowSmB,
    const u64* __restrict__ colPkB, const float* __restrict__ colSmB, int slotBase,
    const float* __restrict__ R, const float* __restrict__ relwt,
    float* __restrict__ pairSq, int* __restrict__ pairCnt) {
    __shared__ unsigned char sA[64 * 80];    // 64 m-rows x 64 k + pad
    __shared__ unsigned char sB[128 * 80];   // 128 c-rows x 64 k + pad
    __shared__ float red[256];
    __shared__ int   mutS[64];
    __shared__ float invS[64];
    int tid = threadIdx.x;
    int ct = blockIdx.x & 1, mt = blockIdx.x >> 1;
    int d = blockIdx.y & 1, zp = blockIdx.y >> 1;
    int iv = (ipack >> (8 * zp)) & 15;
    int jv = (jpack >> (8 * zp)) & 15;
    int slot = slotBase + zp;
    const unsigned char* A = (d ? ET8b : E8b) + (size_t)zp * N_ * N_;
    const unsigned char* B = sf8T + (size_t)(d ? iv : jv) * C_ * N_;
    const u64* faPk = (d ? colPkB : rowPkB) + (size_t)slot * N_;
    const u64* baPk = (d ? rowPkB : colPkB) + (size_t)slot * N_;
    const float* sumE = (d ? colSmB : rowSmB) + (size_t)slot * N_;
    const float* Rr = R + (size_t)(d ? jv : iv) * N_ * C_;
    int pid = d ? (jv * 4 + iv) : (iv * 4 + jv);
    int c0 = ct * 128, m0 = mt * 64;
    int w = tid >> 6, l = tid & 63, wm = w & 1, wn = w >> 1;
    int mr = l & 15, q = l >> 4;
    if (tid < 64) {
        int y = m0 + tid;
        unsigned faIdx = 0xFFFFFFFFu - (unsigned)(faPk[y] & 0xFFFFFFFFull);
        unsigned baIdx = 0xFFFFFFFFu - (unsigned)(baPk[faIdx] & 0xFFFFFFFFull);
        mutS[tid] = (baIdx == (unsigned)y) ? 1 : 0;
        invS[tid] = 1.0f / sumE[y];
    }
    f32x4 acc[2][4];
#pragma unroll
    for (int a = 0; a < 2; ++a)
#pragma unroll
        for (int b = 0; b < 4; ++b)
#pragma unroll
            for (int u = 0; u < 4; ++u) acc[a][b][u] = 0.f;

    // staging maps: A 64 rows x 64 B -> thread: row tid>>2, 16B chunk (tid&3)
    //               B 128 rows x 64 B -> thread: row tid>>1, 32B half (tid&1)
    int ra = tid >> 2, ka = (tid & 3) * 16;
    int rb = tid >> 1, kbb = (tid & 1) * 32;
    const unsigned char* Arow = A + (size_t)(m0 + ra) * N_ + ka;
    const unsigned char* Brow = B + (size_t)(c0 + rb) * N_ + kbb;
    uint4 pa  = *(const uint4*)(Arow);
    uint4 pb0 = *(const uint4*)(Brow);
    uint4 pb1 = *(const uint4*)(Brow + 16);
    for (int k0 = 0; k0 < N_; k0 += 64) {
        *(uint4*)(sA + ra * 80 + ka)       = pa;
        *(uint4*)(sB + rb * 80 + kbb)      = pb0;
        *(uint4*)(sB + rb * 80 + kbb + 16) = pb1;
        __syncthreads();
        int kn = k0 + 64;
        if (kn < N_) {
            pa  = *(const uint4*)(Arow + kn);
            pb0 = *(const uint4*)(Brow + kn);
            pb1 = *(const uint4*)(Brow + kn + 16);
        }
#pragma unroll
        for (int ksub = 0; ksub < 64; ksub += 32) {
            long af[2], bf[4];
#pragma unroll
            for (int ti = 0; ti < 2; ++ti)
                af[ti] = *(const long*)(sA + (wm * 32 + ti * 16 + mr) * 80 + ksub + q * 8);
#pragma unroll
            for (int tj = 0; tj < 4; ++tj)
                bf[tj] = *(const long*)(sB + (wn * 64 + tj * 16 + mr) * 80 + ksub + q * 8);
#pragma unroll
            for (int ti = 0; ti < 2; ++ti)
#pragma unroll
                for (int tj = 0; tj < 4; ++tj)
                    acc[ti][tj] = __builtin_amdgcn_mfma_f32_16x16x32_fp8_fp8(
                        af[ti], bf[tj], acc[ti][tj], 0, 0, 0);
        }
        __syncthreads();
    }
    const float* rw = relwt + (size_t)pid * C_;
    float local = 0.f;
#pragma unroll
    for (int ti = 0; ti < 2; ++ti)
#pragma unroll
        for (int tj = 0; tj < 4; ++tj) {
            int c = c0 + wn * 64 + tj * 16 + mr;
            float rwc = rw[c];
#pragma unroll
            for (int rg = 0; rg < 4; ++rg) {
                int ml = wm * 32 + ti * 16 + q * 4 + rg;
                if (mutS[ml]) {
                    int m = m0 + ml;
                    float soft = acc[ti][tj][rg] * invS[ml];
                    float dv = Rr[(size_t)m * C_ + c] + rwc - soft;
                    local += dv * dv;
                }
            }
        }
    red[tid] = local;
    __syncthreads();
    for (int s = 128; s > 0; s >>= 1) {
        if (tid < s) red[tid] += red[tid + s];
        __syncthreads();
    }
    if (tid == 0) {
        atomicAdd(pairSq + pid, red[0]);
        if (ct == 0) {
            int cnt = 0;
            for (int u = 0; u < 64; ++u) cnt += mutS[u];
            atomicAdd(pairCnt + pid, cnt);
        }
    }
}

// ---- final scalar combine ----
__global__ void final_k(const float* __restrict__ sq, const int* __restrict__ cnt,
                        float* __restrict__ out) {
    if (threadIdx.x == 0 && blockIdx.x == 0) {
        float loss = 0.f, count = 0.f;
        for (int p = 0; p < 16; ++p) {
            int i = p >> 2, j = p & 3;
            if (i == j) continue;
            float ns = (float)cnt[p];
            if (ns > 0.f) { loss += sq[p] / fmaxf(ns * (float)C_, 1.0f); count += 1.f; }
        }
        out[0] = (count > 0.f) ? loss / count : 0.f;
    }
}

extern "C" void kernel_launch(void* const* d_in, const int* in_sizes, int n_in,
                              void* d_out, int out_size, void* d_ws, size_t ws_size,
                              hipStream_t stream) {
    const float* desc = (const float*)d_in[0];
    const float* sf   = (const float*)d_in[1];
    const float* T    = (const float*)d_in[2];
    const float* Wrec = (const float*)d_in[3];
    const float* WT   = (const float*)d_in[4];
    float* out = (float*)d_out;
    char* ws = (char*)d_ws;

    float*          R     = (float*)(ws + OFF_R);
    unsigned short* dnh   = (unsigned short*)(ws + OFF_DNHI);
    unsigned short* dnl   = (unsigned short*)(ws + OFF_DNLO);
    unsigned char*  sf8T  = (unsigned char*)(ws + OFF_SFT);
    unsigned char*  E8b   = (unsigned char*)(ws + OFF_E);
    unsigned char*  ET8b  = (unsigned char*)(ws + OFF_ET);
    unsigned short* WTh   = (unsigned short*)(ws + OFF_WTH);
    unsigned short* WTl   = (unsigned short*)(ws + OFF_WTL);
    u64*   rowPk = (u64*)(ws + OFF_ROWPK);
    u64*   colPk = (u64*)(ws + OFF_COLPK);
    float* rowSm = (float*)(ws + OFF_ROWSM);
    float* colSm = (float*)(ws + OFF_COLSM);
    float* relwt = (float*)(ws + OFF_RELWT);
    float* pairSq = (float*)(ws + OFF_SQ);
    int*   pairCnt = (int*)(ws + OFF_CNT);

    normalize_k<<<N_ * V_, 256, 0, stream>>>(desc, dnh, dnl);
    wrecT_k<<<dim3(4, 4), 256, 0, stream>>>(Wrec, WTh, WTl);
    rmatmul_k<<<dim3(2, 128), 256, 0, stream>>>(dnh, dnl, WTh, WTl, R);
    sfT_k<<<dim3(64, 4, 4), 256, 0, stream>>>(sf, sf8T);
    relwt_k<<<16, 256, 0, stream>>>(T, WT, relwt);
    zero_k<<<96, 256, 0, stream>>>(rowPk, colPk, rowSm, colSm, pairSq, pairCnt);

    // batch 0: pairs (0,1),(0,2),(0,3); batch 1: (1,2),(1,3),(2,3)
    const int ip[2] = { 0 | (0 << 8) | (0 << 16), 1 | (1 << 8) | (2 << 16) };
    const int jp[2] = { 1 | (2 << 8) | (3 << 16), 2 | (3 << 8) | (3 << 16) };
    for (int b = 0; b < 2; ++b) {
        sim_mfma_k<<<dim3(64, 64, 3), 256, 0, stream>>>(
            dnh, dnl, ip[b], jp[b], E8b, ET8b, rowPk, rowSm, colPk, colSm, b * 3);
        p2_k<<<dim3(128, 6), 256, 0, stream>>>(
            E8b, ET8b, sf8T, ip[b], jp[b], rowPk, rowSm, colPk, colSm, b * 3,
            R, relwt, pairSq, pairCnt);
    }
    final_k<<<1, 64, 0, stream>>>(pairSq, pairCnt, out);
}

// Round 14
// 506.747 us; speedup vs baseline: 2.1452x; 1.0087x over previous
//
#include <hip/hip_runtime.h>
#include <math.h>

#define N_ 4096
#define V_ 4
#define C_ 256

typedef __attribute__((ext_vector_type(8))) short bf16x8;
typedef __attribute__((ext_vector_type(4))) float f32x4;
typedef unsigned long long u64;

// ---------------- workspace byte offsets ----------------
#define OFF_R      0ull            // f32 R[v][n][c]          16MB
#define OFF_DNHI   16777216ull     // bf16                     8MB
#define OFF_DNLO   25165824ull     // bf16                     8MB
#define OFF_SFT    33554432ull     // fp8 sfT[v][c][n]         4MB
#define OFF_E      37748736ull     // fp8 E slots x3          48MB
#define OFF_ET     88080384ull     // fp8 ET slots x3         48MB
#define OFF_WTH    138412032ull    // bf16 WT hi 256x256     128KB
#define OFF_WTL    138543104ull
#define OFF_ROWPK  138674176ull    // u64 rowPk[6][4096]     192KB
#define OFF_COLPK  138870784ull    // u64 colPk[6][4096]
#define OFF_ROWSM  139067392ull    // f32 rowSm[6][4096]      96KB
#define OFF_COLSM  139165696ull
#define OFF_RELWT  139264000ull    // f32 16x256
#define OFF_SQ     139280384ull
#define OFF_CNT    139280448ull

__device__ __forceinline__ unsigned short f2bf(float x) {
    unsigned int u = __float_as_uint(x);
    u += 0x7fffu + ((u >> 16) & 1u);
    return (unsigned short)(u >> 16);
}
__device__ __forceinline__ float bf2f(unsigned short h) {
    return __uint_as_float(((unsigned int)h) << 16);
}
__device__ __forceinline__ f32x4 mfma16(bf16x8 a, bf16x8 b, f32x4 c) {
    return __builtin_amdgcn_mfma_f32_16x16x32_bf16(a, b, c, 0, 0, 0);
}
__device__ __forceinline__ unsigned int pk4fp8(float x0, float x1, float x2, float x3) {
    int w = 0;
    w = __builtin_amdgcn_cvt_pk_fp8_f32(x0, x1, w, false);
    w = __builtin_amdgcn_cvt_pk_fp8_f32(x2, x3, w, true);
    return (unsigned int)w;
}

// ---- normalize + bf16 hi/lo split: dn[v][n][c] ----
__global__ void normalize_k(const float* __restrict__ desc,
                            unsigned short* __restrict__ dnh, unsigned short* __restrict__ dnl) {
    int row = blockIdx.x;            // n*V + v
    int n = row >> 2, v = row & 3;
    int c = threadIdx.x;
    float x = desc[(size_t)row * C_ + c];
    __shared__ float red[256];
    red[c] = x * x;
    __syncthreads();
    for (int s = 128; s > 0; s >>= 1) {
        if (c < s) red[c] += red[c + s];
        __syncthreads();
    }
    float inv = 1.0f / fmaxf(sqrtf(red[0]), 1e-12f);
    float y = x * inv;
    size_t o = ((size_t)v * N_ + n) * C_ + c;
    unsigned short h = f2bf(y);
    dnh[o] = h;
    dnl[o] = f2bf(y - bf2f(h));
}

// ---- WT[c][k] = W_rec[k][c], hi/lo bf16 split ----
__global__ void wrecT_k(const float* __restrict__ W, unsigned short* __restrict__ WTh,
                        unsigned short* __restrict__ WTl) {
    __shared__ float Tt[64 * 65];
    int k0 = blockIdx.x * 64, c0 = blockIdx.y * 64;
    int t = threadIdx.x;
    int kr = t >> 2, cq = (t & 3) * 16;
    const float* src = W + (size_t)(k0 + kr) * C_ + c0 + cq;
    for (int u = 0; u < 16; ++u) Tt[(cq + u) * 65 + kr] = src[u];
    __syncthreads();
    int cr = t >> 2, kq = (t & 3) * 16;
    unsigned short th[16] __attribute__((aligned(16)));
    unsigned short tl[16] __attribute__((aligned(16)));
    for (int u = 0; u < 16; ++u) {
        float x = Tt[cr * 65 + kq + u];
        unsigned short h = f2bf(x);
        th[u] = h; tl[u] = f2bf(x - bf2f(h));
    }
    size_t o = (size_t)(c0 + cr) * C_ + k0 + kq;
    *(uint4*)(WTh + o) = *(const uint4*)th;
    *(uint4*)(WTh + o + 8) = *(const uint4*)(th + 8);
    *(uint4*)(WTl + o) = *(const uint4*)tl;
    *(uint4*)(WTl + o + 8) = *(const uint4*)(tl + 8);
}

// ---- R = dn @ W_rec via split-bf16 MFMA; block 128x128, wave 64x64 ----
__global__ __launch_bounds__(256) void rmatmul_k(
    const unsigned short* __restrict__ Ah, const unsigned short* __restrict__ Al,
    const unsigned short* __restrict__ Bh, const unsigned short* __restrict__ Bl,
    float* __restrict__ R) {
    __shared__ unsigned short smem[4 * 128 * 40];
    unsigned short* sAh = smem;
    unsigned short* sAl = sAh + 128 * 40;
    unsigned short* sBh = sAl + 128 * 40;
    unsigned short* sBl = sBh + 128 * 40;
    int tid = threadIdx.x;
    int c0 = blockIdx.x * 128, m0 = blockIdx.y * 128;
    int w = tid >> 6, l = tid & 63, wm = w & 1, wn = w >> 1;
    int mr = l & 15, q = l >> 4;
    f32x4 acc[4][4];
#pragma unroll
    for (int a = 0; a < 4; ++a)
#pragma unroll
        for (int b = 0; b < 4; ++b)
#pragma unroll
            for (int u = 0; u < 4; ++u) acc[a][b][u] = 0.f;
    int r = tid >> 1, h = (tid & 1) * 16;
    for (int k0 = 0; k0 < C_; k0 += 32) {
        size_t ga = (size_t)(m0 + r) * C_ + k0 + h;
        size_t gb = (size_t)(c0 + r) * C_ + k0 + h;
        uint4 a0 = *(const uint4*)(Ah + ga);
        uint4 a1 = *(const uint4*)(Ah + ga + 8);
        uint4 a2 = *(const uint4*)(Al + ga);
        uint4 a3 = *(const uint4*)(Al + ga + 8);
        uint4 b0 = *(const uint4*)(Bh + gb);
        uint4 b1 = *(const uint4*)(Bh + gb + 8);
        uint4 b2 = *(const uint4*)(Bl + gb);
        uint4 b3 = *(const uint4*)(Bl + gb + 8);
        *(uint4*)(sAh + r * 40 + h)     = a0;
        *(uint4*)(sAh + r * 40 + h + 8) = a1;
        *(uint4*)(sAl + r * 40 + h)     = a2;
        *(uint4*)(sAl + r * 40 + h + 8) = a3;
        *(uint4*)(sBh + r * 40 + h)     = b0;
        *(uint4*)(sBh + r * 40 + h + 8) = b1;
        *(uint4*)(sBl + r * 40 + h)     = b2;
        *(uint4*)(sBl + r * 40 + h + 8) = b3;
        __syncthreads();
        bf16x8 fah[4], fal[4], fbh[4], fbl[4];
#pragma unroll
        for (int ti = 0; ti < 4; ++ti) {
            int row = wm * 64 + ti * 16 + mr;
            fah[ti] = *(const bf16x8*)(sAh + row * 40 + q * 8);
            fal[ti] = *(const bf16x8*)(sAl + row * 40 + q * 8);
        }
#pragma unroll
        for (int tj = 0; tj < 4; ++tj) {
            int row = wn * 64 + tj * 16 + mr;
            fbh[tj] = *(const bf16x8*)(sBh + row * 40 + q * 8);
            fbl[tj] = *(const bf16x8*)(sBl + row * 40 + q * 8);
        }
#pragma unroll
        for (int ti = 0; ti < 4; ++ti)
#pragma unroll
            for (int tj = 0; tj < 4; ++tj) acc[ti][tj] = mfma16(fah[ti], fbh[tj], acc[ti][tj]);
#pragma unroll
        for (int ti = 0; ti < 4; ++ti)
#pragma unroll
            for (int tj = 0; tj < 4; ++tj) acc[ti][tj] = mfma16(fah[ti], fbl[tj], acc[ti][tj]);
#pragma unroll
        for (int ti = 0; ti < 4; ++ti)
#pragma unroll
            for (int tj = 0; tj < 4; ++tj) acc[ti][tj] = mfma16(fal[ti], fbh[tj], acc[ti][tj]);
        __syncthreads();
    }
#pragma unroll
    for (int ti = 0; ti < 4; ++ti)
#pragma unroll
        for (int tj = 0; tj < 4; ++tj) {
            int c = c0 + wn * 64 + tj * 16 + mr;
#pragma unroll
            for (int rg = 0; rg < 4; ++rg) {
                int m = m0 + wm * 64 + ti * 16 + q * 4 + rg;
                R[(size_t)m * C_ + c] = acc[ti][tj][rg];
            }
        }
}

// ---- relWT[p][c], p = i*4+j ----
__global__ void relwt_k(const float* __restrict__ T, const float* __restrict__ WT,
                        float* __restrict__ relwt) {
    int p = blockIdx.x; int i = p >> 2, j = p & 3;
    if (i == j) return;
    int c = threadIdx.x;
    float acc = 0.f;
    for (int k = 0; k < 16; ++k) acc += T[i * 16 + k] * WT[(size_t)k * C_ + c];
    for (int k = 0; k < 16; ++k) acc += T[j * 16 + k] * WT[(size_t)(16 + k) * C_ + c];
    relwt[(size_t)p * C_ + c] = acc;
}

// ---- sf8T[v][c][n] = fp8(sf[n][v][c]) ----
__global__ void sfT_k(const float* __restrict__ sf, unsigned char* __restrict__ sf8T) {
    __shared__ float Tt[64 * 65];
    int n0 = blockIdx.x * 64, c0 = blockIdx.y * 64, v = blockIdx.z;
    int t = threadIdx.x;
    int nr = t >> 2, cq = (t & 3) * 16;
    const float* src = sf + ((size_t)(n0 + nr) * V_ + v) * C_ + c0 + cq;
    for (int u = 0; u < 16; ++u) Tt[(cq + u) * 65 + nr] = src[u];
    __syncthreads();
    int cr = t >> 2, nq = (t & 3) * 16;
    unsigned int wb[4];
#pragma unroll
    for (int g = 0; g < 4; ++g) {
        const float* p = Tt + cr * 65 + nq + g * 4;
        wb[g] = pk4fp8(p[0], p[1], p[2], p[3]);
    }
    unsigned char* dst = sf8T + ((size_t)v * C_ + c0 + cr) * N_ + n0 + nq;
    *(uint4*)dst = make_uint4(wb[0], wb[1], wb[2], wb[3]);
}

// ---- zero stats (all 6 slots) + pair accumulators ----
__global__ void zero_k(u64* rowPk, u64* colPk, float* rowSm, float* colSm,
                       float* sq, int* cnt) {
    int idx = blockIdx.x * 256 + threadIdx.x;   // grid 96 -> 24576
    rowPk[idx] = 0ull; colPk[idx] = 0ull;
    rowSm[idx] = 0.f;  colSm[idx] = 0.f;
    if (idx < 16) { sq[idx] = 0.f; cnt[idx] = 0; }
}

// ---- sim: 64x64 tile, split-bf16 3-term, reg-prefetched staging,
//      exp-once, fp8 E/ET, atomic stats. grid (64, 64, 3 pairs) ----
__global__ __launch_bounds__(256) void sim_mfma_k(
    const unsigned short* __restrict__ dnh, const unsigned short* __restrict__ dnl,
    int ipack, int jpack, unsigned char* __restrict__ E8b, unsigned char* __restrict__ ET8b,
    u64* __restrict__ rowPkB, float* __restrict__ rowSmB,
    u64* __restrict__ colPkB, float* __restrict__ colSmB, int slotBase) {
    __shared__ unsigned char smem[36864];
    __shared__ float sRedM[256];
    __shared__ int   sRedA[256];
    __shared__ float sRedS[256];
    unsigned short* sAh = (unsigned short*)smem;          // [64][72]
    unsigned short* sAl = sAh + 64 * 72;
    unsigned short* sBh = sAl + 64 * 72;
    unsigned short* sBl = sBh + 64 * 72;
    float* S = (float*)smem;                               // [64][65] alias, holds expS

    int zp = blockIdx.z;
    int iv = (ipack >> (8 * zp)) & 15;
    int jv = (jpack >> (8 * zp)) & 15;
    const unsigned short* Ahi = dnh + (size_t)iv * N_ * C_;
    const unsigned short* Alo = dnl + (size_t)iv * N_ * C_;
    const unsigned short* Bhi = dnh + (size_t)jv * N_ * C_;
    const unsigned short* Blo = dnl + (size_t)jv * N_ * C_;
    unsigned char* E8  = E8b  + (size_t)zp * N_ * N_;
    unsigned char* ET8 = ET8b + (size_t)zp * N_ * N_;
    int slot = slotBase + zp;
    u64*   rowPk = rowPkB + (size_t)slot * N_;
    float* rowSm = rowSmB + (size_t)slot * N_;
    u64*   colPk = colPkB + (size_t)slot * N_;
    float* colSm = colSmB + (size_t)slot * N_;

    int tid = threadIdx.x;
    int m0 = blockIdx.y * 64, n0 = blockIdx.x * 64;
    int w = tid >> 6, l = tid & 63;
    int wm = w & 1, wn = w >> 1;
    int mr = l & 15, q = l >> 4;

    f32x4 acc[2][2];
#pragma unroll
    for (int a = 0; a < 2; ++a)
#pragma unroll
        for (int b = 0; b < 2; ++b)
#pragma unroll
            for (int u = 0; u < 4; ++u) acc[a][b][u] = 0.f;

    int r = tid >> 2;
    int k8 = (tid & 3) * 8;
    const unsigned short* gAh = Ahi + (size_t)(m0 + r) * C_ + k8;
    const unsigned short* gAl = Alo + (size_t)(m0 + r) * C_ + k8;
    const unsigned short* gBh = Bhi + (size_t)(n0 + r) * C_ + k8;
    const unsigned short* gBl = Blo + (size_t)(n0 + r) * C_ + k8;

    uint4 a0 = *(const uint4*)(gAh);
    uint4 a1 = *(const uint4*)(gAh + 32);
    uint4 a2 = *(const uint4*)(gAl);
    uint4 a3 = *(const uint4*)(gAl + 32);
    uint4 b0 = *(const uint4*)(gBh);
    uint4 b1 = *(const uint4*)(gBh + 32);
    uint4 b2 = *(const uint4*)(gBl);
    uint4 b3 = *(const uint4*)(gBl + 32);

    for (int k0 = 0; k0 < C_; k0 += 64) {
        *(uint4*)(sAh + r * 72 + k8)      = a0;
        *(uint4*)(sAh + r * 72 + k8 + 32) = a1;
        *(uint4*)(sAl + r * 72 + k8)      = a2;
        *(uint4*)(sAl + r * 72 + k8 + 32) = a3;
        *(uint4*)(sBh + r * 72 + k8)      = b0;
        *(uint4*)(sBh + r * 72 + k8 + 32) = b1;
        *(uint4*)(sBl + r * 72 + k8)      = b2;
        *(uint4*)(sBl + r * 72 + k8 + 32) = b3;
        __syncthreads();
        int kn = k0 + 64;
        if (kn < C_) {      // prefetch next K-chunk; vmcnt awaited at next staging write
            a0 = *(const uint4*)(gAh + kn);
            a1 = *(const uint4*)(gAh + kn + 32);
            a2 = *(const uint4*)(gAl + kn);
            a3 = *(const uint4*)(gAl + kn + 32);
            b0 = *(const uint4*)(gBh + kn);
            b1 = *(const uint4*)(gBh + kn + 32);
            b2 = *(const uint4*)(gBl + kn);
            b3 = *(const uint4*)(gBl + kn + 32);
        }
#pragma unroll
        for (int ks = 0; ks < 64; ks += 32) {
            bf16x8 ah[2], al[2], bh[2], bl[2];
#pragma unroll
            for (int ti = 0; ti < 2; ++ti) {
                int mrow = wm * 32 + ti * 16 + mr;
                ah[ti] = *(const bf16x8*)(sAh + mrow * 72 + ks + q * 8);
                al[ti] = *(const bf16x8*)(sAl + mrow * 72 + ks + q * 8);
            }
#pragma unroll
            for (int tj = 0; tj < 2; ++tj) {
                int nrow = wn * 32 + tj * 16 + mr;
                bh[tj] = *(const bf16x8*)(sBh + nrow * 72 + ks + q * 8);
                bl[tj] = *(const bf16x8*)(sBl + nrow * 72 + ks + q * 8);
            }
#pragma unroll
            for (int ti = 0; ti < 2; ++ti)
#pragma unroll
                for (int tj = 0; tj < 2; ++tj) {
                    acc[ti][tj] = mfma16(ah[ti], bh[tj], acc[ti][tj]);
                    acc[ti][tj] = mfma16(ah[ti], bl[tj], acc[ti][tj]);
                    acc[ti][tj] = mfma16(al[ti], bh[tj], acc[ti][tj]);
                }
        }
        __syncthreads();
    }

    // ---- epilogue: exp once into LDS ----
#pragma unroll
    for (int ti = 0; ti < 2; ++ti)
#pragma unroll
        for (int tj = 0; tj < 2; ++tj)
#pragma unroll
            for (int rg = 0; rg < 4; ++rg)
                S[(wm * 32 + ti * 16 + q * 4 + rg) * 65 + wn * 32 + tj * 16 + mr] =
                    __expf(acc[ti][tj][rg]);
    __syncthreads();

    // row stats -> atomics
    {
        int rr = tid >> 2, q4 = tid & 3;
        float mx = -1e30f; int ag = 0; float sm = 0.f;
        for (int cc = 0; cc < 16; ++cc) {
            int c = q4 * 16 + cc;
            float v = S[rr * 65 + c];
            sm += v;
            if (v > mx) { mx = v; ag = c; }
        }
        sRedM[tid] = mx; sRedA[tid] = ag; sRedS[tid] = sm;
    }
    __syncthreads();
    if (tid < 64) {
        float mx = -1e30f; int ag = 0; float sm = 0.f;
        for (int qq = 0; qq < 4; ++qq) {
            float v = sRedM[tid * 4 + qq];
            if (v > mx) { mx = v; ag = sRedA[tid * 4 + qq]; }
            sm += sRedS[tid * 4 + qq];
        }
        u64 pk = ((u64)__float_as_uint(mx) << 32) | (u64)(0xFFFFFFFFu - (unsigned)(n0 + ag));
        atomicMax(rowPk + m0 + tid, pk);
        atomicAdd(rowSm + m0 + tid, sm);
    }
    __syncthreads();
    // col stats -> atomics
    {
        int cc = tid >> 2, q4 = tid & 3;
        float mx = -1e30f; int ag = 0; float sm = 0.f;
        for (int rr = 0; rr < 16; ++rr) {
            int rrr = q4 * 16 + rr;
            float v = S[rrr * 65 + cc];
            sm += v;
            if (v > mx) { mx = v; ag = rrr; }
        }
        sRedM[tid] = mx; sRedA[tid] = ag; sRedS[tid] = sm;
    }
    __syncthreads();
    if (tid < 64) {
        float mx = -1e30f; int ag = 0; float sm = 0.f;
        for (int qq = 0; qq < 4; ++qq) {
            float v = sRedM[tid * 4 + qq];
            if (v > mx) { mx = v; ag = sRedA[tid * 4 + qq]; }
            sm += sRedS[tid * 4 + qq];
        }
        u64 pk = ((u64)__float_as_uint(mx) << 32) | (u64)(0xFFFFFFFFu - (unsigned)(m0 + ag));
        atomicMax(colPk + n0 + tid, pk);
        atomicAdd(colSm + n0 + tid, sm);
    }
    // E store (fp8), row-major
    {
        int r2 = tid >> 2, cq = (tid & 3) * 16;
        unsigned int wb[4];
#pragma unroll
        for (int g = 0; g < 4; ++g) {
            const float* p = S + r2 * 65 + cq + g * 4;
            wb[g] = pk4fp8(p[0], p[1], p[2], p[3]);
        }
        *(uint4*)(E8 + (size_t)(m0 + r2) * N_ + n0 + cq) = make_uint4(wb[0], wb[1], wb[2], wb[3]);
    }
    // ET store (fp8), row-major in n
    {
        int n2 = tid >> 2, mq = (tid & 3) * 16;
        unsigned int wb[4];
#pragma unroll
        for (int g = 0; g < 4; ++g) {
            wb[g] = pk4fp8(S[(mq + g * 4 + 0) * 65 + n2], S[(mq + g * 4 + 1) * 65 + n2],
                           S[(mq + g * 4 + 2) * 65 + n2], S[(mq + g * 4 + 3) * 65 + n2]);
        }
        *(uint4*)(ET8 + (size_t)(n0 + n2) * N_ + m0 + mq) = make_uint4(wb[0], wb[1], wb[2], wb[3]);
    }
}

// ---- pass2 v3: fp8 GEMM 64m x 128c, K-chunk 64, pitch-80 LDS, fused loss ----
// grid: (128, 6): bx -> ct = bx&1 (c half), mt = bx>>1; by -> d = by&1, zp = by>>1
__global__ __launch_bounds__(256) void p2_k(
    const unsigned char* __restrict__ E8b, const unsigned char* __restrict__ ET8b,
    const unsigned char* __restrict__ sf8T, int ipack, int jpack,
    const u64* __restrict__ rowPkB, const float* __restrict__ rowSmB,
    const u64* __restrict__ colPkB, const float* __restrict__ colSmB, int slotBase,
    const float* __restrict__ R, const float* __restrict__ relwt,
    float* __restrict__ pairSq, int* __restrict__ pairCnt) {
    __shared__ unsigned char sA[64 * 80];    // 64 m-rows x 64 k + pad
    __shared__ unsigned char sB[128 * 80];   // 128 c-rows x 64 k + pad
    __shared__ float red[256];
    __shared__ int   mutS[64];
    __shared__ float invS[64];
    int tid = threadIdx.x;
    int ct = blockIdx.x & 1, mt = blockIdx.x >> 1;
    int d = blockIdx.y & 1, zp = blockIdx.y >> 1;
    int iv = (ipack >> (8 * zp)) & 15;
    int jv = (jpack >> (8 * zp)) & 15;
    int slot = slotBase + zp;
    const unsigned char* A = (d ? ET8b : E8b) + (size_t)zp * N_ * N_;
    const unsigned char* B = sf8T + (size_t)(d ? iv : jv) * C_ * N_;
    const u64* faPk = (d ? colPkB : rowPkB) + (size_t)slot * N_;
    const u64* baPk = (d ? rowPkB : colPkB) + (size_t)slot * N_;
    const float* sumE = (d ? colSmB : rowSmB) + (size_t)slot * N_;
    const float* Rr = R + (size_t)(d ? jv : iv) * N_ * C_;
    int pid = d ? (jv * 4 + iv) : (iv * 4 + jv);
    int c0 = ct * 128, m0 = mt * 64;
    int w = tid >> 6, l = tid & 63, wm = w & 1, wn = w >> 1;
    int mr = l & 15, q = l >> 4;
    if (tid < 64) {
        int y = m0 + tid;
        unsigned faIdx = 0xFFFFFFFFu - (unsigned)(faPk[y] & 0xFFFFFFFFull);
        unsigned baIdx = 0xFFFFFFFFu - (unsigned)(baPk[faIdx] & 0xFFFFFFFFull);
        mutS[tid] = (baIdx == (unsigned)y) ? 1 : 0;
        invS[tid] = 1.0f / sumE[y];
    }
    f32x4 acc[2][4];
#pragma unroll
    for (int a = 0; a < 2; ++a)
#pragma unroll
        for (int b = 0; b < 4; ++b)
#pragma unroll
            for (int u = 0; u < 4; ++u) acc[a][b][u] = 0.f;

    int ra = tid >> 2, ka = (tid & 3) * 16;
    int rb = tid >> 1, kbb = (tid & 1) * 32;
    const unsigned char* Arow = A + (size_t)(m0 + ra) * N_ + ka;
    const unsigned char* Brow = B + (size_t)(c0 + rb) * N_ + kbb;
    uint4 pa  = *(const uint4*)(Arow);
    uint4 pb0 = *(const uint4*)(Brow);
    uint4 pb1 = *(const uint4*)(Brow + 16);
    for (int k0 = 0; k0 < N_; k0 += 64) {
        *(uint4*)(sA + ra * 80 + ka)       = pa;
        *(uint4*)(sB + rb * 80 + kbb)      = pb0;
        *(uint4*)(sB + rb * 80 + kbb + 16) = pb1;
        __syncthreads();
        int kn = k0 + 64;
        if (kn < N_) {
            pa  = *(const uint4*)(Arow + kn);
            pb0 = *(const uint4*)(Brow + kn);
            pb1 = *(const uint4*)(Brow + kn + 16);
        }
#pragma unroll
        for (int ksub = 0; ksub < 64; ksub += 32) {
            long af[2], bf[4];
#pragma unroll
            for (int ti = 0; ti < 2; ++ti)
                af[ti] = *(const long*)(sA + (wm * 32 + ti * 16 + mr) * 80 + ksub + q * 8);
#pragma unroll
            for (int tj = 0; tj < 4; ++tj)
                bf[tj] = *(const long*)(sB + (wn * 64 + tj * 16 + mr) * 80 + ksub + q * 8);
#pragma unroll
            for (int ti = 0; ti < 2; ++ti)
#pragma unroll
                for (int tj = 0; tj < 4; ++tj)
                    acc[ti][tj] = __builtin_amdgcn_mfma_f32_16x16x32_fp8_fp8(
                        af[ti], bf[tj], acc[ti][tj], 0, 0, 0);
        }
        __syncthreads();
    }
    const float* rw = relwt + (size_t)pid * C_;
    float local = 0.f;
#pragma unroll
    for (int ti = 0; ti < 2; ++ti)
#pragma unroll
        for (int tj = 0; tj < 4; ++tj) {
            int c = c0 + wn * 64 + tj * 16 + mr;
            float rwc = rw[c];
#pragma unroll
            for (int rg = 0; rg < 4; ++rg) {
                int ml = wm * 32 + ti * 16 + q * 4 + rg;
                if (mutS[ml]) {
                    int m = m0 + ml;
                    float soft = acc[ti][tj][rg] * invS[ml];
                    float dv = Rr[(size_t)m * C_ + c] + rwc - soft;
                    local += dv * dv;
                }
            }
        }
    red[tid] = local;
    __syncthreads();
    for (int s = 128; s > 0; s >>= 1) {
        if (tid < s) red[tid] += red[tid + s];
        __syncthreads();
    }
    if (tid == 0) {
        atomicAdd(pairSq + pid, red[0]);
        if (ct == 0) {
            int cnt = 0;
            for (int u = 0; u < 64; ++u) cnt += mutS[u];
            atomicAdd(pairCnt + pid, cnt);
        }
    }
}

// ---- final scalar combine ----
__global__ void final_k(const float* __restrict__ sq, const int* __restrict__ cnt,
                        float* __restrict__ out) {
    if (threadIdx.x == 0 && blockIdx.x == 0) {
        float loss = 0.f, count = 0.f;
        for (int p = 0; p < 16; ++p) {
            int i = p >> 2, j = p & 3;
            if (i == j) continue;
            float ns = (float)cnt[p];
            if (ns > 0.f) { loss += sq[p] / fmaxf(ns * (float)C_, 1.0f); count += 1.f; }
        }
        out[0] = (count > 0.f) ? loss / count : 0.f;
    }
}

extern "C" void kernel_launch(void* const* d_in, const int* in_sizes, int n_in,
                              void* d_out, int out_size, void* d_ws, size_t ws_size,
                              hipStream_t stream) {
    const float* desc = (const float*)d_in[0];
    const float* sf   = (const float*)d_in[1];
    const float* T    = (const float*)d_in[2];
    const float* Wrec = (const float*)d_in[3];
    const float* WT   = (const float*)d_in[4];
    float* out = (float*)d_out;
    char* ws = (char*)d_ws;

    float*          R     = (float*)(ws + OFF_R);
    unsigned short* dnh   = (unsigned short*)(ws + OFF_DNHI);
    unsigned short* dnl   = (unsigned short*)(ws + OFF_DNLO);
    unsigned char*  sf8T  = (unsigned char*)(ws + OFF_SFT);
    unsigned char*  E8b   = (unsigned char*)(ws + OFF_E);
    unsigned char*  ET8b  = (unsigned char*)(ws + OFF_ET);
    unsigned short* WTh   = (unsigned short*)(ws + OFF_WTH);
    unsigned short* WTl   = (unsigned short*)(ws + OFF_WTL);
    u64*   rowPk = (u64*)(ws + OFF_ROWPK);
    u64*   colPk = (u64*)(ws + OFF_COLPK);
    float* rowSm = (float*)(ws + OFF_ROWSM);
    float* colSm = (float*)(ws + OFF_COLSM);
    float* relwt = (float*)(ws + OFF_RELWT);
    float* pairSq = (float*)(ws + OFF_SQ);
    int*   pairCnt = (int*)(ws + OFF_CNT);

    normalize_k<<<N_ * V_, 256, 0, stream>>>(desc, dnh, dnl);
    wrecT_k<<<dim3(4, 4), 256, 0, stream>>>(Wrec, WTh, WTl);
    rmatmul_k<<<dim3(2, 128), 256, 0, stream>>>(dnh, dnl, WTh, WTl, R);
    sfT_k<<<dim3(64, 4, 4), 256, 0, stream>>>(sf, sf8T);
    relwt_k<<<16, 256, 0, stream>>>(T, WT, relwt);
    zero_k<<<96, 256, 0, stream>>>(rowPk, colPk, rowSm, colSm, pairSq, pairCnt);

    // batch 0: pairs (0,1),(0,2),(0,3); batch 1: (1,2),(1,3),(2,3)
    const int ip[2] = { 0 | (0 << 8) | (0 << 16), 1 | (1 << 8) | (2 << 16) };
    const int jp[2] = { 1 | (2 << 8) | (3 << 16), 2 | (3 << 8) | (3 << 16) };
    for (int b = 0; b < 2; ++b) {
        sim_mfma_k<<<dim3(64, 64, 3), 256, 0, stream>>>(
            dnh, dnl, ip[b], jp[b], E8b, ET8b, rowPk, rowSm, colPk, colSm, b * 3);
        p2_k<<<dim3(128, 6), 256, 0, stream>>>(
            E8b, ET8b, sf8T, ip[b], jp[b], rowPk, rowSm, colPk, colSm, b * 3,
            R, relwt, pairSq, pairCnt);
    }
    final_k<<<1, 64, 0, stream>>>(pairSq, pairCnt, out);
}